// Round 12
// baseline (84.735 us; speedup 1.0000x reference)
//
#include <hip/hip_runtime.h>

// EquAttentionPerChannel on MI355X (gfx950).
// R12: gemm_sd_qkv rebuilt on the m201 8-phase cadence: BM=128 x BSP=128,
//      BK=32 (16 K-tiles), 4 LDS slots (128KB), depth-3 prefetch with counted
//      vmcnt(8) gates, 2 fine phases per K-tile (ds_read quadrant || stage ||
//      barrier || lgkm0 || 8 MFMA || barrier). prep/attn/gemm_out_sd = R11.

typedef unsigned short ushort_t;
typedef __attribute__((ext_vector_type(4))) unsigned short ushort4_t;
typedef __attribute__((ext_vector_type(8))) unsigned short ushort8;
typedef __attribute__((ext_vector_type(8))) __bf16 bf16x8;
typedef __attribute__((ext_vector_type(4))) float f32x4;
typedef __attribute__((ext_vector_type(4))) unsigned int uint4_t;

#define GPTR(p) ((const __attribute__((address_space(1))) void*)(p))
#define LPTR(p) ((__attribute__((address_space(3))) void*)(p))

static __device__ __forceinline__ unsigned short f2b(float f) {   // RNE
  unsigned int u = __builtin_bit_cast(unsigned int, f);
  unsigned int r = u + 0x7fffu + ((u >> 16) & 1u);
  return (unsigned short)(r >> 16);
}
static __device__ __forceinline__ float b2f(ushort_t h) {
  unsigned int u = ((unsigned int)h) << 16;
  return __builtin_bit_cast(float, u);
}
static __device__ __forceinline__ unsigned int pack_rtna(float a, float b) {
  const unsigned int ua = (__builtin_bit_cast(unsigned int, a) + 0x8000u) >> 16;
  const unsigned int ub = (__builtin_bit_cast(unsigned int, b) + 0x8000u) & 0xFFFF0000u;
  return ub | ua;
}

// ---------------------------------------------------------------------------
// Prep (unchanged): xsd + Wsd = [Sq;Dq;Sk;Dk;Sv;Dv;Sp;Dp].
// ---------------------------------------------------------------------------
__global__ __launch_bounds__(256) void prep_k(
    const float* __restrict__ x,
    const float* __restrict__ wqA, const float* __restrict__ wqB,
    const float* __restrict__ wkA, const float* __restrict__ wkB,
    const float* __restrict__ wvA, const float* __restrict__ wvB,
    const float* __restrict__ wpA, const float* __restrict__ wpB,
    ushort_t* __restrict__ xsd, ushort_t* __restrict__ Wsd, float sclq) {
  const int bid = blockIdx.x;
  if (bid < 1024) {
    const int u = bid * 256 + threadIdx.x;
    const int m = u >> 6;
    const int k8 = (u & 63) * 8;
    const float* p1 = x + (size_t)m * 1024 + k8;
    const float* p2 = p1 + 512;
    const f32x4 a0 = *(const f32x4*)p1,  a1 = *(const f32x4*)(p1 + 4);
    const f32x4 b0 = *(const f32x4*)p2,  b1 = *(const f32x4*)(p2 + 4);
    ushort8 vs, vd;
#pragma unroll
    for (int e = 0; e < 4; ++e) {
      vs[e] = f2b(a0[e] + b0[e]); vs[e + 4] = f2b(a1[e] + b1[e]);
      vd[e] = f2b(a0[e] - b0[e]); vd[e + 4] = f2b(a1[e] - b1[e]);
    }
    *(ushort8*)&xsd[(size_t)m * 1024 + k8] = vs;
    *(ushort8*)&xsd[(size_t)m * 1024 + 512 + k8] = vd;
  } else {
    const int u = (bid - 1024) * 256 + threadIdx.x;
    const int hm = u >> 15;
    const int rem = u & 32767;
    const int r = rem >> 6;
    const int c8 = (rem & 63) * 8;
    const int proj = hm >> 1, isD = hm & 1;
    const float* A; const float* B;
    if (proj == 0)      { A = wqA; B = wqB; }
    else if (proj == 1) { A = wkA; B = wkB; }
    else if (proj == 2) { A = wvA; B = wvB; }
    else                { A = wpA; B = wpB; }
    const float scl = 0.5f * (proj == 0 ? sclq : 1.0f);
    const f32x4 a0 = *(const f32x4*)(A + (size_t)r * 512 + c8);
    const f32x4 a1 = *(const f32x4*)(A + (size_t)r * 512 + c8 + 4);
    const f32x4 b0 = *(const f32x4*)(B + (size_t)r * 512 + c8);
    const f32x4 b1 = *(const f32x4*)(B + (size_t)r * 512 + c8 + 4);
    ushort8 v;
#pragma unroll
    for (int e = 0; e < 4; ++e) {
      v[e]     = f2b(isD ? (a0[e] - b0[e]) * scl : (a0[e] + b0[e]) * scl);
      v[e + 4] = f2b(isD ? (a1[e] - b1[e]) * scl : (a1[e] + b1[e]) * scl);
    }
    *(ushort8*)&Wsd[(size_t)(proj * 1024 + isD * 512 + r) * 512 + c8] = v;
  }
}

// ---------------------------------------------------------------------------
// Spectral QKV GEMM R12 (8-phase cadence): block = 128m x 128sp -> y[128][256].
// 512 thr: wave wid: wm=wid>>2, sp=(wid>>1)&1, half=wid&1. K=512, BK=32,
// 16 K-tiles, 4 slots x 32KB (XS@0|XD@4096|S@8192|D@12288 elems), depth-3
// prefetch (stage kt+3), vmcnt(8) counted, 2 phases/K-tile.
// Grid 384 = 8 XCD x 48 (mt=c*4+(j&3); nz=j>>2: z=nz>>2, st=nz&3).
// ---------------------------------------------------------------------------
__global__ __launch_bounds__(512, 2) void gemm_sd_qkv(const ushort_t* __restrict__ xsd,
                                                      const ushort_t* __restrict__ Wsd,
                                                      ushort_t* __restrict__ Qb,
                                                      ushort_t* __restrict__ Kb,
                                                      ushort_t* __restrict__ Vtb) {
  __shared__ ushort_t sh[65536];   // 4 slots x 16384 elems = 128 KB; epilogue reuse

  const int t = threadIdx.x;
  const int wid = t >> 6, lane = t & 63;
  const int wm = wid >> 2, sp = (wid >> 1) & 1, half = wid & 1;
  const int lr = lane & 15, lg = lane >> 4;

  const int bid = blockIdx.x;            // 384
  const int c = bid & 7, j = bid >> 3;   // XCD c, j 0..47
  const int mt = c * 4 + (j & 3);        // 32 m-tiles
  const int nz = j >> 2;                 // 0..11
  const int z = nz >> 2;                 // proj 0..2
  const int n0sp = (nz & 3) * 128;       // spectral col base 0..384
  const int m0 = mt * 128;

  const int srow = t >> 2, scs = t & 3;  // staging row/chunk for this thread
  const int sswz = (scs ^ ((srow >> 1) & 3)) << 3;

  f32x4 acc[4][4];
  const f32x4 fz = {0.f, 0.f, 0.f, 0.f};
#pragma unroll
  for (int mf = 0; mf < 4; ++mf)
#pragma unroll
    for (int nf = 0; nf < 4; ++nf) acc[mf][nf] = fz;

#define STAGE_X(kt_, s_)                                                                 \
  {                                                                                      \
    ushort_t* b_ = sh + (s_) * 16384;                                                    \
    const int gcol = (kt_) * 32 + sswz;                                                  \
    __builtin_amdgcn_global_load_lds(GPTR(xsd + (size_t)(m0 + srow) * 1024 + gcol),      \
                                     LPTR(b_ + (size_t)t * 8), 16, 0, 0);                \
    __builtin_amdgcn_global_load_lds(GPTR(xsd + (size_t)(m0 + srow) * 1024 + 512 + gcol),\
                                     LPTR(b_ + 4096 + (size_t)t * 8), 16, 0, 0);         \
  }
#define STAGE_W(kt_, s_)                                                                 \
  {                                                                                      \
    ushort_t* b_ = sh + (s_) * 16384;                                                    \
    const int gcol = (kt_) * 32 + sswz;                                                  \
    __builtin_amdgcn_global_load_lds(                                                    \
        GPTR(Wsd + (size_t)(z * 1024 + n0sp + srow) * 512 + gcol),                       \
        LPTR(b_ + 8192 + (size_t)t * 8), 16, 0, 0);                                      \
    __builtin_amdgcn_global_load_lds(                                                    \
        GPTR(Wsd + (size_t)(z * 1024 + 512 + n0sp + srow) * 512 + gcol),                 \
        LPTR(b_ + 12288 + (size_t)t * 8), 16, 0, 0);                                     \
  }

  // prologue: tiles 0,1,2 staged; gate tile 0
  STAGE_X(0, 0) STAGE_W(0, 0)
  STAGE_X(1, 1) STAGE_W(1, 1)
  STAGE_X(2, 2) STAGE_W(2, 2)
  asm volatile("s_waitcnt vmcnt(8)" ::: "memory");
  __builtin_amdgcn_sched_barrier(0);
  __builtin_amdgcn_s_barrier();
  asm volatile("" ::: "memory");

  for (int kt = 0; kt < 16; ++kt) {
    const int s = kt & 3;
    const ushort_t* base = sh + s * 16384;
    const ushort_t* Asl = base + half * 4096;           // XS or XD [128][32]
    const ushort_t* Bsl = base + 8192 + half * 4096;    // S or D  [128][32]

    // ---- phase A: frags a0,a1 + b0..b3; stage XS/XD of kt+3; 8 MFMA ----
    bf16x8 a0, a1, b[4];
    {
      const int r0 = wm * 64 + 0 * 16 + lr;
      const int r1 = wm * 64 + 1 * 16 + lr;
      a0 = *(const bf16x8*)&Asl[r0 * 32 + ((lg ^ ((r0 >> 1) & 3)) << 3)];
      a1 = *(const bf16x8*)&Asl[r1 * 32 + ((lg ^ ((r1 >> 1) & 3)) << 3)];
#pragma unroll
      for (int nf = 0; nf < 4; ++nf) {
        const int rb = sp * 64 + nf * 16 + lr;
        b[nf] = *(const bf16x8*)&Bsl[rb * 32 + ((lg ^ ((rb >> 1) & 3)) << 3)];
      }
    }
    if (kt <= 12) STAGE_X(kt + 3, (kt + 3) & 3)
    __builtin_amdgcn_s_barrier();
    asm volatile("s_waitcnt lgkmcnt(0)" ::: "memory");
    __builtin_amdgcn_sched_barrier(0);
    __builtin_amdgcn_s_setprio(1);
#pragma unroll
    for (int nf = 0; nf < 4; ++nf) {
      acc[0][nf] = __builtin_amdgcn_mfma_f32_16x16x32_bf16(a0, b[nf], acc[0][nf], 0, 0, 0);
      acc[1][nf] = __builtin_amdgcn_mfma_f32_16x16x32_bf16(a1, b[nf], acc[1][nf], 0, 0, 0);
    }
    __builtin_amdgcn_s_setprio(0);
    __builtin_amdgcn_s_barrier();
    asm volatile("" ::: "memory");

    // ---- phase B: frags a2,a3; stage S/D of kt+3; vmcnt gate; 8 MFMA ----
    bf16x8 a2, a3;
    {
      const int r2 = wm * 64 + 2 * 16 + lr;
      const int r3 = wm * 64 + 3 * 16 + lr;
      a2 = *(const bf16x8*)&Asl[r2 * 32 + ((lg ^ ((r2 >> 1) & 3)) << 3)];
      a3 = *(const bf16x8*)&Asl[r3 * 32 + ((lg ^ ((r3 >> 1) & 3)) << 3)];
    }
    if (kt <= 12) STAGE_W(kt + 3, (kt + 3) & 3)
    if (kt <= 12) {
      asm volatile("s_waitcnt vmcnt(8)" ::: "memory");   // tile kt+1 landed
    } else if (kt == 13) {
      asm volatile("s_waitcnt vmcnt(4)" ::: "memory");
    } else if (kt == 14) {
      asm volatile("s_waitcnt vmcnt(0)" ::: "memory");
    }
    __builtin_amdgcn_sched_barrier(0);
    __builtin_amdgcn_s_barrier();
    asm volatile("s_waitcnt lgkmcnt(0)" ::: "memory");
    __builtin_amdgcn_sched_barrier(0);
    __builtin_amdgcn_s_setprio(1);
#pragma unroll
    for (int nf = 0; nf < 4; ++nf) {
      acc[2][nf] = __builtin_amdgcn_mfma_f32_16x16x32_bf16(a2, b[nf], acc[2][nf], 0, 0, 0);
      acc[3][nf] = __builtin_amdgcn_mfma_f32_16x16x32_bf16(a3, b[nf], acc[3][nf], 0, 0, 0);
    }
    __builtin_amdgcn_s_setprio(0);
    __builtin_amdgcn_s_barrier();
    asm volatile("" ::: "memory");
  }
#undef STAGE_X
#undef STAGE_W

  // ---- Epilogue: exchange us/vd via LDS, butterfly, store ----
  __syncthreads();
  const int PAD = (z < 2) ? 136 : 137;
  ushort_t* tus = sh;
  ushort_t* tvd = sh + 128 * PAD;
  {
    ushort_t* dst = half ? tvd : tus;
#pragma unroll
    for (int mf = 0; mf < 4; ++mf)
#pragma unroll
      for (int nf = 0; nf < 4; ++nf)
#pragma unroll
        for (int rr = 0; rr < 4; ++rr) {
          const int row = wm * 64 + mf * 16 + lg * 4 + rr;
          const int col = sp * 64 + nf * 16 + lr;
          dst[row * PAD + col] = f2b(acc[mf][nf][rr]);
        }
  }
  __syncthreads();

  if (z < 2) {
    ushort_t* C = (z == 0) ? Qb : Kb;
#pragma unroll
    for (int it = 0; it < 4; ++it) {
      const int idx = it * 512 + t;
      const int row = idx >> 4;            // 0..127
      const int c8 = (idx & 15) * 8;       // 0..120
      const ushort8 u8 = *(const ushort8*)&tus[row * 136 + c8];
      const ushort8 v8 = *(const ushort8*)&tvd[row * 136 + c8];
      ushort8 y1, y2;
#pragma unroll
      for (int e = 0; e < 8; ++e) {
        const float us = b2f(u8[e]), vd = b2f(v8[e]);
        y1[e] = f2b(us + vd);
        y2[e] = f2b(us - vd);
      }
      *(ushort8*)&C[(size_t)(m0 + row) * 1024 + n0sp + c8] = y1;
      *(ushort8*)&C[(size_t)(m0 + row) * 1024 + 512 + n0sp + c8] = y2;
    }
  } else {
    // V: transpose + per-64 key permutation for attn's in-register PV A-frag
    const int bidx = m0 >> 10, tok0 = m0 & 1023;
#pragma unroll
    for (int it = 0; it < 4; ++it) {
      const int idx = it * 512 + t;
      const int cr = idx >> 4;             // spectral channel 0..127
      const int mc = (idx & 15) * 8;       // token chunk 0..120
      float y1v[8], y2v[8];
#pragma unroll
      for (int e = 0; e < 8; ++e) {
        const float us = b2f(tus[(mc + e) * 137 + cr]);
        const float vd = b2f(tvd[(mc + e) * 137 + cr]);
        y1v[e] = us + vd;
        y2v[e] = us - vd;
      }
      const int k6 = mc & 63;
      const int base = (k6 & 0x20) | ((k6 & 8) << 1) | ((k6 & 0x10) >> 2);
      const size_t rb1 = (size_t)bidx * 1024 * 1024 + (size_t)(n0sp + cr) * 1024 +
                         tok0 + (mc & ~63) + base;
      const size_t rb2 = (size_t)bidx * 1024 * 1024 + (size_t)(512 + n0sp + cr) * 1024 +
                         tok0 + (mc & ~63) + base;
      ushort4_t lo1, hi1, lo2, hi2;
#pragma unroll
      for (int e = 0; e < 4; ++e) {
        lo1[e] = f2b(y1v[e]); hi1[e] = f2b(y1v[e + 4]);
        lo2[e] = f2b(y2v[e]); hi2[e] = f2b(y2v[e + 4]);
      }
      *(ushort4_t*)&Vtb[rb1] = lo1;  *(ushort4_t*)&Vtb[rb1 + 8] = hi1;
      *(ushort4_t*)&Vtb[rb2] = lo2;  *(ushort4_t*)&Vtb[rb2 + 8] = hi2;
    }
  }
}

// ---------------------------------------------------------------------------
// Flash attention (unchanged from R11/R10): head-paired (hp, hp+16), 512 thr,
// writes Os/Od for the spectral out-proj.
// ---------------------------------------------------------------------------
__global__ __launch_bounds__(512, 4) void attn_k(const ushort_t* __restrict__ Q,
                                                 const ushort_t* __restrict__ K,
                                                 const ushort_t* __restrict__ Vt,
                                                 ushort_t* __restrict__ Osd) {
  __shared__ ushort_t shmem[32768];
  ushort_t* KsL = shmem;
  ushort_t* VsL = shmem + 16384;
  float* obuf = (float*)shmem;

  const int t = threadIdx.x;
  const int w = t >> 6, lane = t & 63;
  const int hw = w >> 2;
  const int lr = lane & 15, lg = lane >> 4, lk8 = lg * 8;
  const int rkey = (lr >> 1) & 3;
  const int pkey = lr & 7;

  const int nlin = blockIdx.x;          // 0..511
  const int c = nlin & 7, j = nlin >> 3;
  const int p = c * 8 + (j >> 3);
  const int qb = j & 7;
  const int hp = p & 15, b = p >> 4;

  const size_t bbase = (size_t)b * 1024 * 1024;
  const size_t headc = (size_t)hp * 32 + hw * 512;
  const int q0 = qb * 128 + (w & 3) * 32;
  const f32x4 fzero = {0.f, 0.f, 0.f, 0.f};

  bf16x8 bq[2];
#pragma unroll
  for (int i = 0; i < 2; ++i)
    bq[i] = *(const bf16x8*)&Q[bbase + (size_t)(q0 + i * 16 + lr) * 1024 + headc + lk8];

  f32x4 oacc[2][2];
  float tq[2] = {0.f, 0.f};
#pragma unroll
  for (int i = 0; i < 2; ++i)
#pragma unroll
    for (int jj = 0; jj < 2; ++jj) oacc[i][jj] = fzero;

#define ISSUE_KV(kt_, s_)                                                                \
  {                                                                                      \
    ushort_t* Kd_ = KsL + (s_) * 4096;                                                   \
    ushort_t* Vd_ = VsL + (s_) * 4096;                                                   \
    const int hl = t >> 8, rem = t & 255;                                                \
    const size_t hc_ = (size_t)hp * 32 + hl * 512;                                       \
    const int krow = rem >> 2, kc = rem & 3;                                             \
    __builtin_amdgcn_global_load_lds(                                                    \
        GPTR(K + bbase + (size_t)((kt_) * 64 + krow) * 1024 + hc_ +                      \
             ((kc ^ ((krow >> 1) & 3)) << 3)),                                           \
        LPTR(Kd_ + (size_t)t * 8), 16, 0, 0);                                            \
    const int vrow = rem >> 3, vc = rem & 7;                                             \
    __builtin_amdgcn_global_load_lds(                                                    \
        GPTR(Vt + bbase + (size_t)(hc_ + vrow) * 1024 + (kt_) * 64 +                     \
             ((vc ^ (vrow & 7)) << 3)),                                                  \
        LPTR(Vd_ + (size_t)t * 8), 16, 0, 0);                                            \
  }

  ISSUE_KV(0, 0) ISSUE_KV(1, 1) ISSUE_KV(2, 2)
  for (int kt = 0; kt < 16; ++kt) {
    const int s = kt & 3;
    asm volatile("" ::: "memory");
    __builtin_amdgcn_s_barrier();
    asm volatile("" ::: "memory");
    if (kt < 13) {
      ISSUE_KV(kt + 3, (kt + 3) & 3)
      asm volatile("s_waitcnt vmcnt(6)" ::: "memory");
    } else if (kt == 13) {
      asm volatile("s_waitcnt vmcnt(4)" ::: "memory");
    } else if (kt == 14) {
      asm volatile("s_waitcnt vmcnt(2)" ::: "memory");
    } else {
      asm volatile("s_waitcnt vmcnt(0)" ::: "memory");
    }
    __builtin_amdgcn_sched_barrier(0);
    __builtin_amdgcn_s_barrier();
    asm volatile("" ::: "memory");

    const ushort_t* Ksb = KsL + s * 4096 + hw * 2048;
    const ushort_t* Vsb = VsL + s * 4096 + hw * 2048;

    bf16x8 ak[4];
#pragma unroll
    for (int kf = 0; kf < 4; ++kf)
      ak[kf] = *(const bf16x8*)&Ksb[(kf * 16 + lr) * 32 + ((lg ^ rkey) << 3)];

    bf16x8 ap[2][2];
#pragma unroll
    for (int i = 0; i < 2; ++i) {
      f32x4 s4[4];
      __builtin_amdgcn_s_setprio(1);
#pragma unroll
      for (int kf = 0; kf < 4; ++kf)
        s4[kf] = __builtin_amdgcn_mfma_f32_16x16x32_bf16(ak[kf], bq[i], fzero, 0, 0, 0);
      __builtin_amdgcn_s_setprio(0);
#pragma unroll
      for (int ks = 0; ks < 2; ++ks) {
        const float p0 = __builtin_amdgcn_exp2f(s4[2 * ks][0]);
        const float p1 = __builtin_amdgcn_exp2f(s4[2 * ks][1]);
        const float p2 = __builtin_amdgcn_exp2f(s4[2 * ks][2]);
        const float p3 = __builtin_amdgcn_exp2f(s4[2 * ks][3]);
        const float p4 = __builtin_amdgcn_exp2f(s4[2 * ks + 1][0]);
        const float p5 = __builtin_amdgcn_exp2f(s4[2 * ks + 1][1]);
        const float p6 = __builtin_amdgcn_exp2f(s4[2 * ks + 1][2]);
        const float p7 = __builtin_amdgcn_exp2f(s4[2 * ks + 1][3]);
        tq[i] += ((p0 + p1) + (p2 + p3)) + ((p4 + p5) + (p6 + p7));
        uint4_t u;
        u[0] = pack_rtna(p0, p1);
        u[1] = pack_rtna(p2, p3);
        u[2] = pack_rtna(p4, p5);
        u[3] = pack_rtna(p6, p7);
        ap[i][ks] = __builtin_bit_cast(bf16x8, u);
      }
    }

#pragma unroll
    for (int ks = 0; ks < 2; ++ks) {
      bf16x8 bv0 = *(const bf16x8*)&Vsb[(0 * 16 + lr) * 64 + ((ks * 32 + lk8) ^ (pkey << 3))];
      bf16x8 bv1 = *(const bf16x8*)&Vsb[(1 * 16 + lr) * 64 + ((ks * 32 + lk8) ^ (pkey << 3))];
      __builtin_amdgcn_s_setprio(1);
#pragma unroll
      for (int i = 0; i < 2; ++i) {
        oacc[i][0] = __builtin_amdgcn_mfma_f32_16x16x32_bf16(ap[i][ks], bv0, oacc[i][0], 0, 0, 0);
        oacc[i][1] = __builtin_amdgcn_mfma_f32_16x16x32_bf16(ap[i][ks], bv1, oacc[i][1], 0, 0, 0);
      }
      __builtin_amdgcn_s_setprio(0);
    }
  }
#undef ISSUE_KV

#pragma unroll
  for (int i = 0; i < 2; ++i) {
    tq[i] += __shfl_xor(tq[i], 16, 64);
    tq[i] += __shfl_xor(tq[i], 32, 64);
  }

  __syncthreads();
#pragma unroll
  for (int i = 0; i < 2; ++i) {
    float inv[4];
#pragma unroll
    for (int r = 0; r < 4; ++r)
      inv[r] = 1.0f / __shfl(tq[i], lg * 4 + r, 64);
#pragma unroll
    for (int jj = 0; jj < 2; ++jj)
#pragma unroll
      for (int r = 0; r < 4; ++r) {
        const int row = (w & 3) * 32 + i * 16 + lg * 4 + r;
        obuf[hw * 4224 + row * 33 + jj * 16 + lr] = oacc[i][jj][r] * inv[r];
      }
  }
  __syncthreads();

  {
    const int row = t >> 2;
    const int c8 = (t & 3) * 8;
    ushort8 vs, vd;
#pragma unroll
    for (int e = 0; e < 8; ++e) {
      const float o0 = obuf[0 * 4224 + row * 33 + c8 + e];
      const float o1 = obuf[1 * 4224 + row * 33 + c8 + e];
      vs[e] = f2b(o0 + o1);
      vd[e] = f2b(o0 - o1);
    }
    const size_t rowg = bbase + (size_t)(qb * 128 + row) * 1024;
    *(ushort8*)&Osd[rowg + hp * 32 + c8] = vs;
    *(ushort8*)&Osd[rowg + 512 + hp * 32 + c8] = vd;
  }
}

// ---------------------------------------------------------------------------
// Spectral output projection (unchanged from R11): 64m x 64sp, 256 thr,
// K=512, BK=32, 3 slots depth-2 vmcnt(8). Grid 512 = 2/CU.
// ---------------------------------------------------------------------------
__global__ __launch_bounds__(256, 4) void gemm_out_sd(const ushort_t* __restrict__ Osd,
                                                      const ushort_t* __restrict__ Wsd,
                                                      float* __restrict__ out) {
  __shared__ ushort_t sh[24576];

  const int t = threadIdx.x;
  const int w = t >> 6, lane = t & 63;
  const int wm = w >> 1, half = w & 1;
  const int lr = lane & 15, lg = lane >> 4;

  const int bid = blockIdx.x;                 // 512
  const int c = bid & 7, j = bid >> 3;
  const int mt = c * 8 + (j & 7);
  const int st = j >> 3;
  const int m0 = mt * 64, n0s = st * 64;

  f32x4 acc[2][4];
  const f32x4 fz = {0.f, 0.f, 0.f, 0.f};
#pragma unroll
  for (int mf = 0; mf < 2; ++mf)
#pragma unroll
    for (int nf = 0; nf < 4; ++nf) acc[mf][nf] = fz;

#define ISSUE_O(kt_, s_)                                                                 \
  {                                                                                      \
    ushort_t* base_ = sh + (s_) * 8192;                                                  \
    const int k0_ = (kt_) * 32;                                                          \
    const int row = t >> 2, kc = t & 3;                                                  \
    const int gcol = k0_ + ((kc ^ ((row >> 1) & 3)) << 3);                               \
    __builtin_amdgcn_global_load_lds(GPTR(Osd + (size_t)(m0 + row) * 1024 + gcol),       \
                                     LPTR(base_ + (size_t)t * 8), 16, 0, 0);             \
    __builtin_amdgcn_global_load_lds(GPTR(Osd + (size_t)(m0 + row) * 1024 + 512 + gcol), \
                                     LPTR(base_ + 2048 + (size_t)t * 8), 16, 0, 0);      \
    __builtin_amdgcn_global_load_lds(                                                    \
        GPTR(Wsd + (size_t)(3072 + n0s + row) * 512 + gcol),                             \
        LPTR(base_ + 4096 + (size_t)t * 8), 16, 0, 0);                                   \
    __builtin_amdgcn_global_load_lds(                                                    \
        GPTR(Wsd + (size_t)(3072 + 512 + n0s + row) * 512 + gcol),                       \
        LPTR(base_ + 6144 + (size_t)t * 8), 16, 0, 0);                                   \
  }

  ISSUE_O(0, 0) ISSUE_O(1, 1)
  int s = 0;
  for (int kt = 0; kt < 16; ++kt) {
    asm volatile("" ::: "memory");
    __builtin_amdgcn_s_barrier();
    asm volatile("" ::: "memory");
    if (kt < 14) {
      const int s2 = (s >= 1) ? s - 1 : 2;       // (kt+2)%3
      ISSUE_O(kt + 2, s2)
      asm volatile("s_waitcnt vmcnt(8)" ::: "memory");
    } else if (kt == 14) {
      asm volatile("s_waitcnt vmcnt(4)" ::: "memory");
    } else {
      asm volatile("s_waitcnt vmcnt(0)" ::: "memory");
    }
    __builtin_amdgcn_sched_barrier(0);
    __builtin_amdgcn_s_barrier();
    asm volatile("" ::: "memory");

    const ushort_t* base = sh + s * 8192;
    const ushort_t* Asl = base + half * 2048;
    const ushort_t* Bsl = base + 4096 + half * 2048;
    bf16x8 a[2], b[4];
#pragma unroll
    for (int mf = 0; mf < 2; ++mf) {
      const int row = wm * 32 + mf * 16 + lr;
      a[mf] = *(const bf16x8*)&Asl[row * 32 + ((lg ^ ((row >> 1) & 3)) << 3)];
    }
#pragma unroll
    for (int nf = 0; nf < 4; ++nf) {
      const int row = nf * 16 + lr;
      b[nf] = *(const bf16x8*)&Bsl[row * 32 + ((lg ^ ((row >> 1) & 3)) << 3)];
    }
    __builtin_amdgcn_s_setprio(1);
#pragma unroll
    for (int mf = 0; mf < 2; ++mf)
#pragma unroll
      for (int nf = 0; nf < 4; ++nf)
        acc[mf][nf] = __builtin_amdgcn_mfma_f32_16x16x32_bf16(a[mf], b[nf], acc[mf][nf], 0, 0, 0);
    __builtin_amdgcn_s_setprio(0);
    s = (s == 2) ? 0 : s + 1;
  }
#undef ISSUE_O

  __syncthreads();
  float* vdbuf = (float*)sh;
  if (half == 1) {
#pragma unroll
    for (int mf = 0; mf < 2; ++mf)
#pragma unroll
      for (int nf = 0; nf < 4; ++nf)
#pragma unroll
        for (int rr = 0; rr < 4; ++rr) {
          const int row = wm * 32 + mf * 16 + lg * 4 + rr;
          const int col = nf * 16 + lr;
          vdbuf[row * 66 + col] = acc[mf][nf][rr];
        }
  }
  __syncthreads();
  if (half == 0) {
#pragma unroll
    for (int mf = 0; mf < 2; ++mf)
#pragma unroll
      for (int nf = 0; nf < 4; ++nf)
#pragma unroll
        for (int rr = 0; rr < 4; ++rr) {
          const int row = wm * 32 + mf * 16 + lg * 4 + rr;
          const int col = nf * 16 + lr;
          const float us = acc[mf][nf][rr];
          const float vd = vdbuf[row * 66 + col];
          out[(size_t)(m0 + row) * 1024 + n0s + col] = us + vd;
          out[(size_t)(m0 + row) * 1024 + 512 + n0s + col] = us - vd;
        }
  }
}

// ---------------------------------------------------------------------------
extern "C" void kernel_launch(void* const* d_in, const int* in_sizes, int n_in,
                              void* d_out, int out_size, void* d_ws, size_t ws_size,
                              hipStream_t stream) {
  const float* x   = (const float*)d_in[0];
  const float* wqA = (const float*)d_in[1];
  const float* wqB = (const float*)d_in[2];
  const float* wkA = (const float*)d_in[3];
  const float* wkB = (const float*)d_in[4];
  const float* wvA = (const float*)d_in[5];
  const float* wvB = (const float*)d_in[6];
  const float* wpA = (const float*)d_in[7];
  const float* wpB = (const float*)d_in[8];
  float* out = (float*)d_out;

  const size_t NE = (size_t)4096 * 1024;
  ushort_t* Qb   = (ushort_t*)d_ws;
  ushort_t* Kb   = Qb + NE;
  ushort_t* Vtb  = Kb + NE;
  ushort_t* xsd  = Vtb + NE;
  ushort_t* Wsd  = xsd + NE;                    // 4096x512 (Sq,Dq,Sk,Dk,Sv,Dv,Sp,Dp)
  ushort_t* Osd  = xsd;                         // alias: xsd dead after gemm_sd_qkv

  const float SCL = 0.17677669529663687f * 1.4426950408889634f;  // hd^-0.5 * log2e

  prep_k<<<2048, 256, 0, stream>>>(x, wqA, wqB, wkA, wkB, wvA, wvB, wpA, wpB,
                                   xsd, Wsd, SCL);
  gemm_sd_qkv<<<384, 512, 0, stream>>>(xsd, Wsd, Qb, Kb, Vtb);
  attn_k<<<512, 512, 0, stream>>>(Qb, Kb, Vtb, Osd);
  gemm_out_sd<<<512, 256, 0, stream>>>(Osd, Wsd, out);

  (void)in_sizes; (void)n_in; (void)out_size; (void)ws_size;
}

// Round 13
// 79.109 us; speedup vs baseline: 1.0711x; 1.0711x over previous
//
#include <hip/hip_runtime.h>

// EquAttentionPerChannel on MI355X (gfx950).
// R13: revert gemm_sd_qkv to R11 (R12's fine-phase port regressed);
//      attn P-pack via v_perm_b32 (3 VALU ops/pair vs 5, bit-identical RTNA).
//      Everything else identical to R11.

typedef unsigned short ushort_t;
typedef __attribute__((ext_vector_type(4))) unsigned short ushort4_t;
typedef __attribute__((ext_vector_type(8))) unsigned short ushort8;
typedef __attribute__((ext_vector_type(8))) __bf16 bf16x8;
typedef __attribute__((ext_vector_type(4))) float f32x4;
typedef __attribute__((ext_vector_type(4))) unsigned int uint4_t;

#define GPTR(p) ((const __attribute__((address_space(1))) void*)(p))
#define LPTR(p) ((__attribute__((address_space(3))) void*)(p))

static __device__ __forceinline__ unsigned short f2b(float f) {   // RNE
  unsigned int u = __builtin_bit_cast(unsigned int, f);
  unsigned int r = u + 0x7fffu + ((u >> 16) & 1u);
  return (unsigned short)(r >> 16);
}
static __device__ __forceinline__ float b2f(ushort_t h) {
  unsigned int u = ((unsigned int)h) << 16;
  return __builtin_bit_cast(float, u);
}
static __device__ __forceinline__ unsigned int pack2_rtna(float a, float b) {
  // [lo16 = bf16_rtna(a), hi16 = bf16_rtna(b)] via 2 adds + 1 v_perm_b32
  const unsigned int ra = __builtin_bit_cast(unsigned int, a) + 0x8000u;
  const unsigned int rb = __builtin_bit_cast(unsigned int, b) + 0x8000u;
  return __builtin_amdgcn_perm(rb, ra, 0x07060302u);  // [ra.b2,ra.b3,rb.b2,rb.b3]
}

// ---------------------------------------------------------------------------
// Prep: xsd (xs=x1+x2, xd=x1-x2) + Wsd = [Sq;Dq;Sk;Dk;Sv;Dv;Sp;Dp], Q scaled.
// ---------------------------------------------------------------------------
__global__ __launch_bounds__(256) void prep_k(
    const float* __restrict__ x,
    const float* __restrict__ wqA, const float* __restrict__ wqB,
    const float* __restrict__ wkA, const float* __restrict__ wkB,
    const float* __restrict__ wvA, const float* __restrict__ wvB,
    const float* __restrict__ wpA, const float* __restrict__ wpB,
    ushort_t* __restrict__ xsd, ushort_t* __restrict__ Wsd, float sclq) {
  const int bid = blockIdx.x;
  if (bid < 1024) {
    const int u = bid * 256 + threadIdx.x;
    const int m = u >> 6;
    const int k8 = (u & 63) * 8;
    const float* p1 = x + (size_t)m * 1024 + k8;
    const float* p2 = p1 + 512;
    const f32x4 a0 = *(const f32x4*)p1,  a1 = *(const f32x4*)(p1 + 4);
    const f32x4 b0 = *(const f32x4*)p2,  b1 = *(const f32x4*)(p2 + 4);
    ushort8 vs, vd;
#pragma unroll
    for (int e = 0; e < 4; ++e) {
      vs[e] = f2b(a0[e] + b0[e]); vs[e + 4] = f2b(a1[e] + b1[e]);
      vd[e] = f2b(a0[e] - b0[e]); vd[e + 4] = f2b(a1[e] - b1[e]);
    }
    *(ushort8*)&xsd[(size_t)m * 1024 + k8] = vs;
    *(ushort8*)&xsd[(size_t)m * 1024 + 512 + k8] = vd;
  } else {
    const int u = (bid - 1024) * 256 + threadIdx.x;
    const int hm = u >> 15;
    const int rem = u & 32767;
    const int r = rem >> 6;
    const int c8 = (rem & 63) * 8;
    const int proj = hm >> 1, isD = hm & 1;
    const float* A; const float* B;
    if (proj == 0)      { A = wqA; B = wqB; }
    else if (proj == 1) { A = wkA; B = wkB; }
    else if (proj == 2) { A = wvA; B = wvB; }
    else                { A = wpA; B = wpB; }
    const float scl = 0.5f * (proj == 0 ? sclq : 1.0f);
    const f32x4 a0 = *(const f32x4*)(A + (size_t)r * 512 + c8);
    const f32x4 a1 = *(const f32x4*)(A + (size_t)r * 512 + c8 + 4);
    const f32x4 b0 = *(const f32x4*)(B + (size_t)r * 512 + c8);
    const f32x4 b1 = *(const f32x4*)(B + (size_t)r * 512 + c8 + 4);
    ushort8 v;
#pragma unroll
    for (int e = 0; e < 4; ++e) {
      v[e]     = f2b(isD ? (a0[e] - b0[e]) * scl : (a0[e] + b0[e]) * scl);
      v[e + 4] = f2b(isD ? (a1[e] - b1[e]) * scl : (a1[e] + b1[e]) * scl);
    }
    *(ushort8*)&Wsd[(size_t)(proj * 1024 + isD * 512 + r) * 512 + c8] = v;
  }
}

// ---------------------------------------------------------------------------
// Spectral QKV GEMM (R11): 128m x 64sp tile, 256 thr (4 waves: 2M x 2half),
// K=512, BK=32, 2 slots x 24KB (depth-1, vmcnt(6)) -> 48KB LDS, 3 blocks/CU.
// Grid 768 = 3/CU uniform. Butterfly epilogue (incl. V transpose+permute).
// ---------------------------------------------------------------------------
__global__ __launch_bounds__(256, 3) void gemm_sd_qkv(const ushort_t* __restrict__ xsd,
                                                      const ushort_t* __restrict__ Wsd,
                                                      ushort_t* __restrict__ Qb,
                                                      ushort_t* __restrict__ Kb,
                                                      ushort_t* __restrict__ Vtb) {
  __shared__ ushort_t sh[24576];   // 2 slots x 12288; epilogue 2x128x73 = 18688

  const int t = threadIdx.x;
  const int wid = t >> 6, lane = t & 63;
  const int wm = wid >> 1, half = wid & 1;
  const int lr = lane & 15, lg = lane >> 4;

  const int bid = blockIdx.x;            // 768
  const int c = bid & 7, j = bid >> 3;   // j 0..95
  const int mt = c * 4 + (j & 3);        // 32 m-tiles
  const int nzt = j >> 2;                // 0..23
  const int z = nzt >> 3;                // proj
  const int n0 = (nzt & 7) * 64;         // spectral col base
  const int m0 = mt * 128;

  f32x4 acc[4][4];
  const f32x4 fz = {0.f, 0.f, 0.f, 0.f};
#pragma unroll
  for (int mf = 0; mf < 4; ++mf)
#pragma unroll
    for (int nf = 0; nf < 4; ++nf) acc[mf][nf] = fz;

#define ISSUE(kt_, s_)                                                                   \
  {                                                                                      \
    ushort_t* base_ = sh + (s_) * 12288;                                                 \
    const int k0_ = (kt_) * 32;                                                          \
    _Pragma("unroll") for (int rnd = 0; rnd < 2; ++rnd) {                                \
      const int ch = rnd * 256 + t;                                                      \
      const int row = ch >> 2, cs = ch & 3;                                              \
      const int gcol = k0_ + ((cs ^ ((row >> 1) & 3)) << 3);                             \
      __builtin_amdgcn_global_load_lds(GPTR(xsd + (size_t)(m0 + row) * 1024 + gcol),     \
                                       LPTR(base_ + (size_t)ch * 8), 16, 0, 0);          \
      __builtin_amdgcn_global_load_lds(GPTR(xsd + (size_t)(m0 + row) * 1024 + 512 + gcol),\
                                       LPTR(base_ + 4096 + (size_t)ch * 8), 16, 0, 0);   \
    }                                                                                    \
    {                                                                                    \
      const int row = t >> 2, cs = t & 3;                                                \
      const int gcol = k0_ + ((cs ^ ((row >> 1) & 3)) << 3);                             \
      __builtin_amdgcn_global_load_lds(                                                  \
          GPTR(Wsd + (size_t)(z * 1024 + n0 + row) * 512 + gcol),                        \
          LPTR(sh + (s_) * 12288 + 8192 + (size_t)t * 8), 16, 0, 0);                     \
      __builtin_amdgcn_global_load_lds(                                                  \
          GPTR(Wsd + (size_t)(z * 1024 + 512 + n0 + row) * 512 + gcol),                  \
          LPTR(sh + (s_) * 12288 + 10240 + (size_t)t * 8), 16, 0, 0);                    \
    }                                                                                    \
  }

  ISSUE(0, 0)
  for (int kt = 0; kt < 16; ++kt) {
    const int s = kt & 1;
    asm volatile("" ::: "memory");
    __builtin_amdgcn_s_barrier();          // all waves done reading slot s^1
    asm volatile("" ::: "memory");
    if (kt < 15) {
      ISSUE(kt + 1, s ^ 1)
      asm volatile("s_waitcnt vmcnt(6)" ::: "memory");   // slot kt's own loads landed
    } else {
      asm volatile("s_waitcnt vmcnt(0)" ::: "memory");
    }
    __builtin_amdgcn_sched_barrier(0);
    __builtin_amdgcn_s_barrier();          // all waves' slot kt landed
    asm volatile("" ::: "memory");

    const ushort_t* base = sh + s * 12288;
    const ushort_t* Asl = base + half * 4096;           // xs or xd
    const ushort_t* Bsl = base + 8192 + half * 2048;    // S or D
    bf16x8 a[4], b[4];
#pragma unroll
    for (int mf = 0; mf < 4; ++mf) {
      const int row = wm * 64 + mf * 16 + lr;
      a[mf] = *(const bf16x8*)&Asl[row * 32 + ((lg ^ ((row >> 1) & 3)) << 3)];
    }
#pragma unroll
    for (int nf = 0; nf < 4; ++nf) {
      const int row = nf * 16 + lr;
      b[nf] = *(const bf16x8*)&Bsl[row * 32 + ((lg ^ ((row >> 1) & 3)) << 3)];
    }
    __builtin_amdgcn_s_setprio(1);
#pragma unroll
    for (int mf = 0; mf < 4; ++mf)
#pragma unroll
      for (int nf = 0; nf < 4; ++nf)
        acc[mf][nf] = __builtin_amdgcn_mfma_f32_16x16x32_bf16(a[mf], b[nf], acc[mf][nf], 0, 0, 0);
    __builtin_amdgcn_s_setprio(0);
  }
#undef ISSUE

  // ---- Epilogue: exchange us/vd via LDS, butterfly, store ----
  __syncthreads();
  const int PAD = (z < 2) ? 72 : 73;
  ushort_t* tus = sh;
  ushort_t* tvd = sh + 128 * PAD;
  {
    ushort_t* dst = half ? tvd : tus;
#pragma unroll
    for (int mf = 0; mf < 4; ++mf)
#pragma unroll
      for (int nf = 0; nf < 4; ++nf)
#pragma unroll
        for (int rr = 0; rr < 4; ++rr) {
          const int row = wm * 64 + mf * 16 + lg * 4 + rr;
          const int col = nf * 16 + lr;
          dst[row * PAD + col] = f2b(acc[mf][nf][rr]);
        }
  }
  __syncthreads();

  if (z < 2) {
    ushort_t* C = (z == 0) ? Qb : Kb;
#pragma unroll
    for (int it = 0; it < 4; ++it) {
      const int idx = it * 256 + t;
      const int row = idx >> 3;            // 0..127
      const int c8 = (idx & 7) * 8;        // 0..56
      const ushort8 u8 = *(const ushort8*)&tus[row * 72 + c8];
      const ushort8 v8 = *(const ushort8*)&tvd[row * 72 + c8];
      ushort8 y1, y2;
#pragma unroll
      for (int e = 0; e < 8; ++e) {
        const float us = b2f(u8[e]), vd = b2f(v8[e]);
        y1[e] = f2b(us + vd);
        y2[e] = f2b(us - vd);
      }
      *(ushort8*)&C[(size_t)(m0 + row) * 1024 + n0 + c8] = y1;
      *(ushort8*)&C[(size_t)(m0 + row) * 1024 + 512 + n0 + c8] = y2;
    }
  } else {
    // V: transpose + per-64 key permutation for attn's in-register PV A-frag
    const int bidx = m0 >> 10, tok0 = m0 & 1023;
#pragma unroll
    for (int it = 0; it < 4; ++it) {
      const int idx = it * 256 + t;
      const int cr = idx >> 4;             // spectral channel 0..63
      const int mc = (idx & 15) * 8;       // token chunk 0..120
      float y1v[8], y2v[8];
#pragma unroll
      for (int e = 0; e < 8; ++e) {
        const float us = b2f(tus[(mc + e) * 73 + cr]);
        const float vd = b2f(tvd[(mc + e) * 73 + cr]);
        y1v[e] = us + vd;
        y2v[e] = us - vd;
      }
      const int k6 = mc & 63;
      const int base = (k6 & 0x20) | ((k6 & 8) << 1) | ((k6 & 0x10) >> 2);
      const size_t rb1 = (size_t)bidx * 1024 * 1024 + (size_t)(n0 + cr) * 1024 +
                         tok0 + (mc & ~63) + base;
      const size_t rb2 = (size_t)bidx * 1024 * 1024 + (size_t)(512 + n0 + cr) * 1024 +
                         tok0 + (mc & ~63) + base;
      ushort4_t lo1, hi1, lo2, hi2;
#pragma unroll
      for (int e = 0; e < 4; ++e) {
        lo1[e] = f2b(y1v[e]); hi1[e] = f2b(y1v[e + 4]);
        lo2[e] = f2b(y2v[e]); hi2[e] = f2b(y2v[e + 4]);
      }
      *(ushort4_t*)&Vtb[rb1] = lo1;  *(ushort4_t*)&Vtb[rb1 + 8] = hi1;
      *(ushort4_t*)&Vtb[rb2] = lo2;  *(ushort4_t*)&Vtb[rb2 + 8] = hi2;
    }
  }
}

// ---------------------------------------------------------------------------
// Flash attention (R11 + perm-pack): head-paired (hp, hp+16), 512 thr,
// writes Os/Od for the spectral out-proj.
// ---------------------------------------------------------------------------
__global__ __launch_bounds__(512, 4) void attn_k(const ushort_t* __restrict__ Q,
                                                 const ushort_t* __restrict__ K,
                                                 const ushort_t* __restrict__ Vt,
                                                 ushort_t* __restrict__ Osd) {
  __shared__ ushort_t shmem[32768];
  ushort_t* KsL = shmem;
  ushort_t* VsL = shmem + 16384;
  float* obuf = (float*)shmem;

  const int t = threadIdx.x;
  const int w = t >> 6, lane = t & 63;
  const int hw = w >> 2;
  const int lr = lane & 15, lg = lane >> 4, lk8 = lg * 8;
  const int rkey = (lr >> 1) & 3;
  const int pkey = lr & 7;

  const int nlin = blockIdx.x;          // 0..511
  const int c = nlin & 7, j = nlin >> 3;
  const int p = c * 8 + (j >> 3);
  const int qb = j & 7;
  const int hp = p & 15, b = p >> 4;

  const size_t bbase = (size_t)b * 1024 * 1024;
  const size_t headc = (size_t)hp * 32 + hw * 512;
  const int q0 = qb * 128 + (w & 3) * 32;
  const f32x4 fzero = {0.f, 0.f, 0.f, 0.f};

  bf16x8 bq[2];
#pragma unroll
  for (int i = 0; i < 2; ++i)
    bq[i] = *(const bf16x8*)&Q[bbase + (size_t)(q0 + i * 16 + lr) * 1024 + headc + lk8];

  f32x4 oacc[2][2];
  float tq[2] = {0.f, 0.f};
#pragma unroll
  for (int i = 0; i < 2; ++i)
#pragma unroll
    for (int jj = 0; jj < 2; ++jj) oacc[i][jj] = fzero;

#define ISSUE_KV(kt_, s_)                                                                \
  {                                                                                      \
    ushort_t* Kd_ = KsL + (s_) * 4096;                                                   \
    ushort_t* Vd_ = VsL + (s_) * 4096;                                                   \
    const int hl = t >> 8, rem = t & 255;                                                \
    const size_t hc_ = (size_t)hp * 32 + hl * 512;                                       \
    const int krow = rem >> 2, kc = rem & 3;                                             \
    __builtin_amdgcn_global_load_lds(                                                    \
        GPTR(K + bbase + (size_t)((kt_) * 64 + krow) * 1024 + hc_ +                      \
             ((kc ^ ((krow >> 1) & 3)) << 3)),                                           \
        LPTR(Kd_ + (size_t)t * 8), 16, 0, 0);                                            \
    const int vrow = rem >> 3, vc = rem & 7;                                             \
    __builtin_amdgcn_global_load_lds(                                                    \
        GPTR(Vt + bbase + (size_t)(hc_ + vrow) * 1024 + (kt_) * 64 +                     \
             ((vc ^ (vrow & 7)) << 3)),                                                  \
        LPTR(Vd_ + (size_t)t * 8), 16, 0, 0);                                            \
  }

  ISSUE_KV(0, 0) ISSUE_KV(1, 1) ISSUE_KV(2, 2)
  for (int kt = 0; kt < 16; ++kt) {
    const int s = kt & 3;
    asm volatile("" ::: "memory");
    __builtin_amdgcn_s_barrier();
    asm volatile("" ::: "memory");
    if (kt < 13) {
      ISSUE_KV(kt + 3, (kt + 3) & 3)
      asm volatile("s_waitcnt vmcnt(6)" ::: "memory");
    } else if (kt == 13) {
      asm volatile("s_waitcnt vmcnt(4)" ::: "memory");
    } else if (kt == 14) {
      asm volatile("s_waitcnt vmcnt(2)" ::: "memory");
    } else {
      asm volatile("s_waitcnt vmcnt(0)" ::: "memory");
    }
    __builtin_amdgcn_sched_barrier(0);
    __builtin_amdgcn_s_barrier();
    asm volatile("" ::: "memory");

    const ushort_t* Ksb = KsL + s * 4096 + hw * 2048;
    const ushort_t* Vsb = VsL + s * 4096 + hw * 2048;

    bf16x8 ak[4];
#pragma unroll
    for (int kf = 0; kf < 4; ++kf)
      ak[kf] = *(const bf16x8*)&Ksb[(kf * 16 + lr) * 32 + ((lg ^ rkey) << 3)];

    bf16x8 ap[2][2];
#pragma unroll
    for (int i = 0; i < 2; ++i) {
      f32x4 s4[4];
      __builtin_amdgcn_s_setprio(1);
#pragma unroll
      for (int kf = 0; kf < 4; ++kf)
        s4[kf] = __builtin_amdgcn_mfma_f32_16x16x32_bf16(ak[kf], bq[i], fzero, 0, 0, 0);
      __builtin_amdgcn_s_setprio(0);
#pragma unroll
      for (int ks = 0; ks < 2; ++ks) {
        const float p0 = __builtin_amdgcn_exp2f(s4[2 * ks][0]);
        const float p1 = __builtin_amdgcn_exp2f(s4[2 * ks][1]);
        const float p2 = __builtin_amdgcn_exp2f(s4[2 * ks][2]);
        const float p3 = __builtin_amdgcn_exp2f(s4[2 * ks][3]);
        const float p4 = __builtin_amdgcn_exp2f(s4[2 * ks + 1][0]);
        const float p5 = __builtin_amdgcn_exp2f(s4[2 * ks + 1][1]);
        const float p6 = __builtin_amdgcn_exp2f(s4[2 * ks + 1][2]);
        const float p7 = __builtin_amdgcn_exp2f(s4[2 * ks + 1][3]);
        tq[i] += ((p0 + p1) + (p2 + p3)) + ((p4 + p5) + (p6 + p7));
        uint4_t u;
        u[0] = pack2_rtna(p0, p1);
        u[1] = pack2_rtna(p2, p3);
        u[2] = pack2_rtna(p4, p5);
        u[3] = pack2_rtna(p6, p7);
        ap[i][ks] = __builtin_bit_cast(bf16x8, u);
      }
    }

#pragma unroll
    for (int ks = 0; ks < 2; ++ks) {
      bf16x8 bv0 = *(const bf16x8*)&Vsb[(0 * 16 + lr) * 64 + ((ks * 32 + lk8) ^ (pkey << 3))];
      bf16x8 bv1 = *(const bf16x8*)&Vsb[(1 * 16 + lr) * 64 + ((ks * 32 + lk8) ^ (pkey << 3))];
      __builtin_amdgcn_s_setprio(1);
#pragma unroll
      for (int i = 0; i < 2; ++i) {
        oacc[i][0] = __builtin_amdgcn_mfma_f32_16x16x32_bf16(ap[i][ks], bv0, oacc[i][0], 0, 0, 0);
        oacc[i][1] = __builtin_amdgcn_mfma_f32_16x16x32_bf16(ap[i][ks], bv1, oacc[i][1], 0, 0, 0);
      }
      __builtin_amdgcn_s_setprio(0);
    }
  }
#undef ISSUE_KV

#pragma unroll
  for (int i = 0; i < 2; ++i) {
    tq[i] += __shfl_xor(tq[i], 16, 64);
    tq[i] += __shfl_xor(tq[i], 32, 64);
  }

  __syncthreads();
#pragma unroll
  for (int i = 0; i < 2; ++i) {
    float inv[4];
#pragma unroll
    for (int r = 0; r < 4; ++r)
      inv[r] = 1.0f / __shfl(tq[i], lg * 4 + r, 64);
#pragma unroll
    for (int jj = 0; jj < 2; ++jj)
#pragma unroll
      for (int r = 0; r < 4; ++r) {
        const int row = (w & 3) * 32 + i * 16 + lg * 4 + r;
        obuf[hw * 4224 + row * 33 + jj * 16 + lr] = oacc[i][jj][r] * inv[r];
      }
  }
  __syncthreads();

  {
    const int row = t >> 2;
    const int c8 = (t & 3) * 8;
    ushort8 vs, vd;
#pragma unroll
    for (int e = 0; e < 8; ++e) {
      const float o0 = obuf[0 * 4224 + row * 33 + c8 + e];
      const float o1 = obuf[1 * 4224 + row * 33 + c8 + e];
      vs[e] = f2b(o0 + o1);
      vd[e] = f2b(o0 - o1);
    }
    const size_t rowg = bbase + (size_t)(qb * 128 + row) * 1024;
    *(ushort8*)&Osd[rowg + hp * 32 + c8] = vs;
    *(ushort8*)&Osd[rowg + 512 + hp * 32 + c8] = vd;
  }
}

// ---------------------------------------------------------------------------
// Spectral output projection (R11): 64m x 64sp, 256 thr, K=512, BK=32,
// 3 slots x 16KB depth-2 (vmcnt(8)). Grid 512 = 2/CU uniform.
// ---------------------------------------------------------------------------
__global__ __launch_bounds__(256, 4) void gemm_out_sd(const ushort_t* __restrict__ Osd,
                                                      const ushort_t* __restrict__ Wsd,
                                                      float* __restrict__ out) {
  __shared__ ushort_t sh[24576];

  const int t = threadIdx.x;
  const int w = t >> 6, lane = t & 63;
  const int wm = w >> 1, half = w & 1;
  const int lr = lane & 15, lg = lane >> 4;

  const int bid = blockIdx.x;                 // 512
  const int c = bid & 7, j = bid >> 3;
  const int mt = c * 8 + (j & 7);
  const int st = j >> 3;
  const int m0 = mt * 64, n0s = st * 64;

  f32x4 acc[2][4];
  const f32x4 fz = {0.f, 0.f, 0.f, 0.f};
#pragma unroll
  for (int mf = 0; mf < 2; ++mf)
#pragma unroll
    for (int nf = 0; nf < 4; ++nf) acc[mf][nf] = fz;

#define ISSUE_O(kt_, s_)                                                                 \
  {                                                                                      \
    ushort_t* base_ = sh + (s_) * 8192;                                                  \
    const int k0_ = (kt_) * 32;                                                          \
    const int row = t >> 2, kc = t & 3;                                                  \
    const int gcol = k0_ + ((kc ^ ((row >> 1) & 3)) << 3);                               \
    __builtin_amdgcn_global_load_lds(GPTR(Osd + (size_t)(m0 + row) * 1024 + gcol),       \
                                     LPTR(base_ + (size_t)t * 8), 16, 0, 0);             \
    __builtin_amdgcn_global_load_lds(GPTR(Osd + (size_t)(m0 + row) * 1024 + 512 + gcol), \
                                     LPTR(base_ + 2048 + (size_t)t * 8), 16, 0, 0);      \
    __builtin_amdgcn_global_load_lds(                                                    \
        GPTR(Wsd + (size_t)(3072 + n0s + row) * 512 + gcol),                             \
        LPTR(base_ + 4096 + (size_t)t * 8), 16, 0, 0);                                   \
    __builtin_amdgcn_global_load_lds(                                                    \
        GPTR(Wsd + (size_t)(3072 + 512 + n0s + row) * 512 + gcol),                       \
        LPTR(base_ + 6144 + (size_t)t * 8), 16, 0, 0);                                   \
  }

  ISSUE_O(0, 0) ISSUE_O(1, 1)
  int s = 0;
  for (int kt = 0; kt < 16; ++kt) {
    asm volatile("" ::: "memory");
    __builtin_amdgcn_s_barrier();
    asm volatile("" ::: "memory");
    if (kt < 14) {
      const int s2 = (s >= 1) ? s - 1 : 2;       // (kt+2)%3
      ISSUE_O(kt + 2, s2)
      asm volatile("s_waitcnt vmcnt(8)" ::: "memory");
    } else if (kt == 14) {
      asm volatile("s_waitcnt vmcnt(4)" ::: "memory");
    } else {
      asm volatile("s_waitcnt vmcnt(0)" ::: "memory");
    }
    __builtin_amdgcn_sched_barrier(0);
    __builtin_amdgcn_s_barrier();
    asm volatile("" ::: "memory");

    const ushort_t* base = sh + s * 8192;
    const ushort_t* Asl = base + half * 2048;
    const ushort_t* Bsl = base + 4096 + half * 2048;
    bf16x8 a[2], b[4];
#pragma unroll
    for (int mf = 0; mf < 2; ++mf) {
      const int row = wm * 32 + mf * 16 + lr;
      a[mf] = *(const bf16x8*)&Asl[row * 32 + ((lg ^ ((row >> 1) & 3)) << 3)];
    }
#pragma unroll
    for (int nf = 0; nf < 4; ++nf) {
      const int row = nf * 16 + lr;
      b[nf] = *(const bf16x8*)&Bsl[row * 32 + ((lg ^ ((row >> 1) & 3)) << 3)];
    }
    __builtin_amdgcn_s_setprio(1);
#pragma unroll
    for (int mf = 0; mf < 2; ++mf)
#pragma unroll
      for (int nf = 0; nf < 4; ++nf)
        acc[mf][nf] = __builtin_amdgcn_mfma_f32_16x16x32_bf16(a[mf], b[nf], acc[mf][nf], 0, 0, 0);
    __builtin_amdgcn_s_setprio(0);
    s = (s == 2) ? 0 : s + 1;
  }
#undef ISSUE_O

  __syncthreads();
  float* vdbuf = (float*)sh;
  if (half == 1) {
#pragma unroll
    for (int mf = 0; mf < 2; ++mf)
#pragma unroll
      for (int nf = 0; nf < 4; ++nf)
#pragma unroll
        for (int rr = 0; rr < 4; ++rr) {
          const int row = wm * 32 + mf * 16 + lg * 4 + rr;
          const int col = nf * 16 + lr;
          vdbuf[row * 66 + col] = acc[mf][nf][rr];
        }
  }
  __syncthreads();
  if (half == 0) {
#pragma unroll
    for (int mf = 0; mf < 2; ++mf)
#pragma unroll
      for (int nf = 0; nf < 4; ++nf)
#pragma unroll
        for (int rr = 0; rr < 4; ++rr) {
          const int row = wm * 32 + mf * 16 + lg * 4 + rr;
          const int col = nf * 16 + lr;
          const float us = acc[mf][nf][rr];
          const float vd = vdbuf[row * 66 + col];
          out[(size_t)(m0 + row) * 1024 + n0s + col] = us + vd;
          out[(size_t)(m0 + row) * 1024 + 512 + n0s + col] = us - vd;
        }
  }
}

// ---------------------------------------------------------------------------
extern "C" void kernel_launch(void* const* d_in, const int* in_sizes, int n_in,
                              void* d_out, int out_size, void* d_ws, size_t ws_size,
                              hipStream_t stream) {
  const float* x   = (const float*)d_in[0];
  const float* wqA = (const float*)d_in[1];
  const float* wqB = (const float*)d_in[2];
  const float* wkA = (const float*)d_in[3];
  const float* wkB = (const float*)d_in[4];
  const float* wvA = (const float*)d_in[5];
  const float* wvB = (const float*)d_in[6];
  const float* wpA = (const float*)d_in[7];
  const float* wpB = (const float*)d_in[8];
  float* out = (float*)d_out;

  const size_t NE = (size_t)4096 * 1024;
  ushort_t* Qb   = (ushort_t*)d_ws;
  ushort_t* Kb   = Qb + NE;
  ushort_t* Vtb  = Kb + NE;
  ushort_t* xsd  = Vtb + NE;
  ushort_t* Wsd  = xsd + NE;                    // 4096x512 (Sq,Dq,Sk,Dk,Sv,Dv,Sp,Dp)
  ushort_t* Osd  = xsd;                         // alias: xsd dead after gemm_sd_qkv

  const float SCL = 0.17677669529663687f * 1.4426950408889634f;  // hd^-0.5 * log2e

  prep_k<<<2048, 256, 0, stream>>>(x, wqA, wqB, wkA, wkB, wvA, wvB, wpA, wpB,
                                   xsd, Wsd, SCL);
  gemm_sd_qkv<<<768, 256, 0, stream>>>(xsd, Wsd, Qb, Kb, Vtb);
  attn_k<<<512, 512, 0, stream>>>(Qb, Kb, Vtb, Osd);
  gemm_out_sd<<<512, 256, 0, stream>>>(Osd, Wsd, out);

  (void)in_sizes; (void)n_in; (void)out_size; (void)ws_size;
}

// Round 14
// 77.376 us; speedup vs baseline: 1.0951x; 1.0224x over previous
//
#include <hip/hip_runtime.h>

// EquAttentionPerChannel on MI355X (gfx950).
// R14: both spectral GEMMs moved to the m97 cadence: BK=64, single LDS buffer,
//      {stage -> vmcnt(0)+barrier -> 32 (resp 16) MFMA over 2 kk -> barrier},
//      3 blocks/CU (QKV) / 2+ blocks/CU (out). Barrier-pairs halved, MFMA per
//      pair doubled. prep / attn byte-identical to R13.

typedef unsigned short ushort_t;
typedef __attribute__((ext_vector_type(4))) unsigned short ushort4_t;
typedef __attribute__((ext_vector_type(8))) unsigned short ushort8;
typedef __attribute__((ext_vector_type(8))) __bf16 bf16x8;
typedef __attribute__((ext_vector_type(4))) float f32x4;
typedef __attribute__((ext_vector_type(4))) unsigned int uint4_t;

#define GPTR(p) ((const __attribute__((address_space(1))) void*)(p))
#define LPTR(p) ((__attribute__((address_space(3))) void*)(p))

static __device__ __forceinline__ unsigned short f2b(float f) {   // RNE
  unsigned int u = __builtin_bit_cast(unsigned int, f);
  unsigned int r = u + 0x7fffu + ((u >> 16) & 1u);
  return (unsigned short)(r >> 16);
}
static __device__ __forceinline__ float b2f(ushort_t h) {
  unsigned int u = ((unsigned int)h) << 16;
  return __builtin_bit_cast(float, u);
}
static __device__ __forceinline__ unsigned int pack2_rtna(float a, float b) {
  const unsigned int ra = __builtin_bit_cast(unsigned int, a) + 0x8000u;
  const unsigned int rb = __builtin_bit_cast(unsigned int, b) + 0x8000u;
  return __builtin_amdgcn_perm(rb, ra, 0x07060302u);  // [ra.b2,ra.b3,rb.b2,rb.b3]
}

// ---------------------------------------------------------------------------
// Prep (unchanged): xsd + Wsd = [Sq;Dq;Sk;Dk;Sv;Dv;Sp;Dp], Q pre-scaled.
// ---------------------------------------------------------------------------
__global__ __launch_bounds__(256) void prep_k(
    const float* __restrict__ x,
    const float* __restrict__ wqA, const float* __restrict__ wqB,
    const float* __restrict__ wkA, const float* __restrict__ wkB,
    const float* __restrict__ wvA, const float* __restrict__ wvB,
    const float* __restrict__ wpA, const float* __restrict__ wpB,
    ushort_t* __restrict__ xsd, ushort_t* __restrict__ Wsd, float sclq) {
  const int bid = blockIdx.x;
  if (bid < 1024) {
    const int u = bid * 256 + threadIdx.x;
    const int m = u >> 6;
    const int k8 = (u & 63) * 8;
    const float* p1 = x + (size_t)m * 1024 + k8;
    const float* p2 = p1 + 512;
    const f32x4 a0 = *(const f32x4*)p1,  a1 = *(const f32x4*)(p1 + 4);
    const f32x4 b0 = *(const f32x4*)p2,  b1 = *(const f32x4*)(p2 + 4);
    ushort8 vs, vd;
#pragma unroll
    for (int e = 0; e < 4; ++e) {
      vs[e] = f2b(a0[e] + b0[e]); vs[e + 4] = f2b(a1[e] + b1[e]);
      vd[e] = f2b(a0[e] - b0[e]); vd[e + 4] = f2b(a1[e] - b1[e]);
    }
    *(ushort8*)&xsd[(size_t)m * 1024 + k8] = vs;
    *(ushort8*)&xsd[(size_t)m * 1024 + 512 + k8] = vd;
  } else {
    const int u = (bid - 1024) * 256 + threadIdx.x;
    const int hm = u >> 15;
    const int rem = u & 32767;
    const int r = rem >> 6;
    const int c8 = (rem & 63) * 8;
    const int proj = hm >> 1, isD = hm & 1;
    const float* A; const float* B;
    if (proj == 0)      { A = wqA; B = wqB; }
    else if (proj == 1) { A = wkA; B = wkB; }
    else if (proj == 2) { A = wvA; B = wvB; }
    else                { A = wpA; B = wpB; }
    const float scl = 0.5f * (proj == 0 ? sclq : 1.0f);
    const f32x4 a0 = *(const f32x4*)(A + (size_t)r * 512 + c8);
    const f32x4 a1 = *(const f32x4*)(A + (size_t)r * 512 + c8 + 4);
    const f32x4 b0 = *(const f32x4*)(B + (size_t)r * 512 + c8);
    const f32x4 b1 = *(const f32x4*)(B + (size_t)r * 512 + c8 + 4);
    ushort8 v;
#pragma unroll
    for (int e = 0; e < 4; ++e) {
      v[e]     = f2b(isD ? (a0[e] - b0[e]) * scl : (a0[e] + b0[e]) * scl);
      v[e + 4] = f2b(isD ? (a1[e] - b1[e]) * scl : (a1[e] + b1[e]) * scl);
    }
    *(ushort8*)&Wsd[(size_t)(proj * 1024 + isD * 512 + r) * 512 + c8] = v;
  }
}

// ---------------------------------------------------------------------------
// Spectral QKV GEMM R14 (m97 cadence): 128m x 64sp tile, 256 thr (2M x 2half),
// K=512, BK=64 (8 K-tiles), single 48KB buffer:
//   XS[128][64]@0 | XD@8192 | S[64][64]@16384 | D@20480  (elems)
// Swizzle: chunk cs of row stored at cs^(row&7); read (kk*4+lg)^(row&7).
// Grid 768 = 3 blocks/CU uniform (cross-block overlap hides staging).
// ---------------------------------------------------------------------------
__global__ __launch_bounds__(256, 3) void gemm_sd_qkv(const ushort_t* __restrict__ xsd,
                                                      const ushort_t* __restrict__ Wsd,
                                                      ushort_t* __restrict__ Qb,
                                                      ushort_t* __restrict__ Kb,
                                                      ushort_t* __restrict__ Vtb) {
  __shared__ ushort_t sh[24576];   // 48KB; epilogue reuse 2x128x73 = 18688 elems

  const int t = threadIdx.x;
  const int wid = t >> 6, lane = t & 63;
  const int wm = wid >> 1, half = wid & 1;
  const int lr = lane & 15, lg = lane >> 4;

  const int bid = blockIdx.x;            // 768
  const int c = bid & 7, j = bid >> 3;   // j 0..95
  const int mt = c * 4 + (j & 3);        // 32 m-tiles
  const int nzt = j >> 2;                // 0..23
  const int z = nzt >> 3;                // proj
  const int n0 = (nzt & 7) * 64;         // spectral col base
  const int m0 = mt * 128;

  f32x4 acc[4][4];
  const f32x4 fz = {0.f, 0.f, 0.f, 0.f};
#pragma unroll
  for (int mf = 0; mf < 4; ++mf)
#pragma unroll
    for (int nf = 0; nf < 4; ++nf) acc[mf][nf] = fz;

#define ISSUE(kt_)                                                                       \
  {                                                                                      \
    _Pragma("unroll") for (int rnd = 0; rnd < 4; ++rnd) {                                \
      const int ch = rnd * 256 + t;                                                      \
      const int row = ch >> 3, cs = ch & 7;                                              \
      const int gcol = (kt_) * 64 + ((cs ^ (row & 7)) << 3);                             \
      __builtin_amdgcn_global_load_lds(GPTR(xsd + (size_t)(m0 + row) * 1024 + gcol),     \
                                       LPTR(sh + (size_t)ch * 8), 16, 0, 0);             \
      __builtin_amdgcn_global_load_lds(GPTR(xsd + (size_t)(m0 + row) * 1024 + 512 + gcol),\
                                       LPTR(sh + 8192 + (size_t)ch * 8), 16, 0, 0);      \
    }                                                                                    \
    _Pragma("unroll") for (int rnd = 0; rnd < 2; ++rnd) {                                \
      const int ch = rnd * 256 + t;                                                      \
      const int row = ch >> 3, cs = ch & 7;                                              \
      const int gcol = (kt_) * 64 + ((cs ^ (row & 7)) << 3);                             \
      __builtin_amdgcn_global_load_lds(                                                  \
          GPTR(Wsd + (size_t)(z * 1024 + n0 + row) * 512 + gcol),                        \
          LPTR(sh + 16384 + (size_t)ch * 8), 16, 0, 0);                                  \
      __builtin_amdgcn_global_load_lds(                                                  \
          GPTR(Wsd + (size_t)(z * 1024 + 512 + n0 + row) * 512 + gcol),                  \
          LPTR(sh + 20480 + (size_t)ch * 8), 16, 0, 0);                                  \
    }                                                                                    \
  }

  const ushort_t* Asl = sh + half * 8192;            // XS or XD [128][64]
  const ushort_t* Bsl = sh + 16384 + half * 4096;    // S or D  [64][64]

  for (int kt = 0; kt < 8; ++kt) {
    ISSUE(kt)
    asm volatile("s_waitcnt vmcnt(0)" ::: "memory");
    __builtin_amdgcn_sched_barrier(0);
    __builtin_amdgcn_s_barrier();        // tile kt fully landed
    asm volatile("" ::: "memory");

#pragma unroll
    for (int kk = 0; kk < 2; ++kk) {
      bf16x8 a[4], b[4];
#pragma unroll
      for (int mf = 0; mf < 4; ++mf) {
        const int row = wm * 64 + mf * 16 + lr;
        a[mf] = *(const bf16x8*)&Asl[row * 64 + (((kk * 4 + lg) ^ (row & 7)) << 3)];
      }
#pragma unroll
      for (int nf = 0; nf < 4; ++nf) {
        const int row = nf * 16 + lr;
        b[nf] = *(const bf16x8*)&Bsl[row * 64 + (((kk * 4 + lg) ^ (row & 7)) << 3)];
      }
      __builtin_amdgcn_s_setprio(1);
#pragma unroll
      for (int mf = 0; mf < 4; ++mf)
#pragma unroll
        for (int nf = 0; nf < 4; ++nf)
          acc[mf][nf] = __builtin_amdgcn_mfma_f32_16x16x32_bf16(a[mf], b[nf], acc[mf][nf], 0, 0, 0);
      __builtin_amdgcn_s_setprio(0);
    }
    asm volatile("s_waitcnt lgkmcnt(0)" ::: "memory");
    __builtin_amdgcn_sched_barrier(0);
    __builtin_amdgcn_s_barrier();        // all waves done reading before next stage
    asm volatile("" ::: "memory");
  }
#undef ISSUE

  // ---- Epilogue: exchange us/vd via LDS, butterfly, store ----
  const int PAD = (z < 2) ? 72 : 73;
  ushort_t* tus = sh;
  ushort_t* tvd = sh + 128 * PAD;
  {
    ushort_t* dst = half ? tvd : tus;
#pragma unroll
    for (int mf = 0; mf < 4; ++mf)
#pragma unroll
      for (int nf = 0; nf < 4; ++nf)
#pragma unroll
        for (int rr = 0; rr < 4; ++rr) {
          const int row = wm * 64 + mf * 16 + lg * 4 + rr;
          const int col = nf * 16 + lr;
          dst[row * PAD + col] = f2b(acc[mf][nf][rr]);
        }
  }
  __syncthreads();

  if (z < 2) {
    ushort_t* C = (z == 0) ? Qb : Kb;
#pragma unroll
    for (int it = 0; it < 4; ++it) {
      const int idx = it * 256 + t;
      const int row = idx >> 3;            // 0..127
      const int c8 = (idx & 7) * 8;        // 0..56
      const ushort8 u8 = *(const ushort8*)&tus[row * 72 + c8];
      const ushort8 v8 = *(const ushort8*)&tvd[row * 72 + c8];
      ushort8 y1, y2;
#pragma unroll
      for (int e = 0; e < 8; ++e) {
        const float us = b2f(u8[e]), vd = b2f(v8[e]);
        y1[e] = f2b(us + vd);
        y2[e] = f2b(us - vd);
      }
      *(ushort8*)&C[(size_t)(m0 + row) * 1024 + n0 + c8] = y1;
      *(ushort8*)&C[(size_t)(m0 + row) * 1024 + 512 + n0 + c8] = y2;
    }
  } else {
    // V: transpose + per-64 key permutation for attn's in-register PV A-frag
    const int bidx = m0 >> 10, tok0 = m0 & 1023;
#pragma unroll
    for (int it = 0; it < 4; ++it) {
      const int idx = it * 256 + t;
      const int cr = idx >> 4;             // spectral channel 0..63
      const int mc = (idx & 15) * 8;       // token chunk 0..120
      float y1v[8], y2v[8];
#pragma unroll
      for (int e = 0; e < 8; ++e) {
        const float us = b2f(tus[(mc + e) * 73 + cr]);
        const float vd = b2f(tvd[(mc + e) * 73 + cr]);
        y1v[e] = us + vd;
        y2v[e] = us - vd;
      }
      const int k6 = mc & 63;
      const int base = (k6 & 0x20) | ((k6 & 8) << 1) | ((k6 & 0x10) >> 2);
      const size_t rb1 = (size_t)bidx * 1024 * 1024 + (size_t)(n0 + cr) * 1024 +
                         tok0 + (mc & ~63) + base;
      const size_t rb2 = (size_t)bidx * 1024 * 1024 + (size_t)(512 + n0 + cr) * 1024 +
                         tok0 + (mc & ~63) + base;
      ushort4_t lo1, hi1, lo2, hi2;
#pragma unroll
      for (int e = 0; e < 4; ++e) {
        lo1[e] = f2b(y1v[e]); hi1[e] = f2b(y1v[e + 4]);
        lo2[e] = f2b(y2v[e]); hi2[e] = f2b(y2v[e + 4]);
      }
      *(ushort4_t*)&Vtb[rb1] = lo1;  *(ushort4_t*)&Vtb[rb1 + 8] = hi1;
      *(ushort4_t*)&Vtb[rb2] = lo2;  *(ushort4_t*)&Vtb[rb2 + 8] = hi2;
    }
  }
}

// ---------------------------------------------------------------------------
// Flash attention (byte-identical to R13): head-paired, perm-pack P,
// writes Os/Od for the spectral out-proj.
// ---------------------------------------------------------------------------
__global__ __launch_bounds__(512, 4) void attn_k(const ushort_t* __restrict__ Q,
                                                 const ushort_t* __restrict__ K,
                                                 const ushort_t* __restrict__ Vt,
                                                 ushort_t* __restrict__ Osd) {
  __shared__ ushort_t shmem[32768];
  ushort_t* KsL = shmem;
  ushort_t* VsL = shmem + 16384;
  float* obuf = (float*)shmem;

  const int t = threadIdx.x;
  const int w = t >> 6, lane = t & 63;
  const int hw = w >> 2;
  const int lr = lane & 15, lg = lane >> 4, lk8 = lg * 8;
  const int rkey = (lr >> 1) & 3;
  const int pkey = lr & 7;

  const int nlin = blockIdx.x;          // 0..511
  const int c = nlin & 7, j = nlin >> 3;
  const int p = c * 8 + (j >> 3);
  const int qb = j & 7;
  const int hp = p & 15, b = p >> 4;

  const size_t bbase = (size_t)b * 1024 * 1024;
  const size_t headc = (size_t)hp * 32 + hw * 512;
  const int q0 = qb * 128 + (w & 3) * 32;
  const f32x4 fzero = {0.f, 0.f, 0.f, 0.f};

  bf16x8 bq[2];
#pragma unroll
  for (int i = 0; i < 2; ++i)
    bq[i] = *(const bf16x8*)&Q[bbase + (size_t)(q0 + i * 16 + lr) * 1024 + headc + lk8];

  f32x4 oacc[2][2];
  float tq[2] = {0.f, 0.f};
#pragma unroll
  for (int i = 0; i < 2; ++i)
#pragma unroll
    for (int jj = 0; jj < 2; ++jj) oacc[i][jj] = fzero;

#define ISSUE_KV(kt_, s_)                                                                \
  {                                                                                      \
    ushort_t* Kd_ = KsL + (s_) * 4096;                                                   \
    ushort_t* Vd_ = VsL + (s_) * 4096;                                                   \
    const int hl = t >> 8, rem = t & 255;                                                \
    const size_t hc_ = (size_t)hp * 32 + hl * 512;                                       \
    const int krow = rem >> 2, kc = rem & 3;                                             \
    __builtin_amdgcn_global_load_lds(                                                    \
        GPTR(K + bbase + (size_t)((kt_) * 64 + krow) * 1024 + hc_ +                      \
             ((kc ^ ((krow >> 1) & 3)) << 3)),                                           \
        LPTR(Kd_ + (size_t)t * 8), 16, 0, 0);                                            \
    const int vrow = rem >> 3, vc = rem & 7;                                             \
    __builtin_amdgcn_global_load_lds(                                                    \
        GPTR(Vt + bbase + (size_t)(hc_ + vrow) * 1024 + (kt_) * 64 +                     \
             ((vc ^ (vrow & 7)) << 3)),                                                  \
        LPTR(Vd_ + (size_t)t * 8), 16, 0, 0);                                            \
  }

  ISSUE_KV(0, 0) ISSUE_KV(1, 1) ISSUE_KV(2, 2)
  for (int kt = 0; kt < 16; ++kt) {
    const int s = kt & 3;
    asm volatile("" ::: "memory");
    __builtin_amdgcn_s_barrier();
    asm volatile("" ::: "memory");
    if (kt < 13) {
      ISSUE_KV(kt + 3, (kt + 3) & 3)
      asm volatile("s_waitcnt vmcnt(6)" ::: "memory");
    } else if (kt == 13) {
      asm volatile("s_waitcnt vmcnt(4)" ::: "memory");
    } else if (kt == 14) {
      asm volatile("s_waitcnt vmcnt(2)" ::: "memory");
    } else {
      asm volatile("s_waitcnt vmcnt(0)" ::: "memory");
    }
    __builtin_amdgcn_sched_barrier(0);
    __builtin_amdgcn_s_barrier();
    asm volatile("" ::: "memory");

    const ushort_t* Ksb = KsL + s * 4096 + hw * 2048;
    const ushort_t* Vsb = VsL + s * 4096 + hw * 2048;

    bf16x8 ak[4];
#pragma unroll
    for (int kf = 0; kf < 4; ++kf)
      ak[kf] = *(const bf16x8*)&Ksb[(kf * 16 + lr) * 32 + ((lg ^ rkey) << 3)];

    bf16x8 ap[2][2];
#pragma unroll
    for (int i = 0; i < 2; ++i) {
      f32x4 s4[4];
      __builtin_amdgcn_s_setprio(1);
#pragma unroll
      for (int kf = 0; kf < 4; ++kf)
        s4[kf] = __builtin_amdgcn_mfma_f32_16x16x32_bf16(ak[kf], bq[i], fzero, 0, 0, 0);
      __builtin_amdgcn_s_setprio(0);
#pragma unroll
      for (int ks = 0; ks < 2; ++ks) {
        const float p0 = __builtin_amdgcn_exp2f(s4[2 * ks][0]);
        const float p1 = __builtin_amdgcn_exp2f(s4[2 * ks][1]);
        const float p2 = __builtin_amdgcn_exp2f(s4[2 * ks][2]);
        const float p3 = __builtin_amdgcn_exp2f(s4[2 * ks][3]);
        const float p4 = __builtin_amdgcn_exp2f(s4[2 * ks + 1][0]);
        const float p5 = __builtin_amdgcn_exp2f(s4[2 * ks + 1][1]);
        const float p6 = __builtin_amdgcn_exp2f(s4[2 * ks + 1][2]);
        const float p7 = __builtin_amdgcn_exp2f(s4[2 * ks + 1][3]);
        tq[i] += ((p0 + p1) + (p2 + p3)) + ((p4 + p5) + (p6 + p7));
        uint4_t u;
        u[0] = pack2_rtna(p0, p1);
        u[1] = pack2_rtna(p2, p3);
        u[2] = pack2_rtna(p4, p5);
        u[3] = pack2_rtna(p6, p7);
        ap[i][ks] = __builtin_bit_cast(bf16x8, u);
      }
    }

#pragma unroll
    for (int ks = 0; ks < 2; ++ks) {
      bf16x8 bv0 = *(const bf16x8*)&Vsb[(0 * 16 + lr) * 64 + ((ks * 32 + lk8) ^ (pkey << 3))];
      bf16x8 bv1 = *(const bf16x8*)&Vsb[(1 * 16 + lr) * 64 + ((ks * 32 + lk8) ^ (pkey << 3))];
      __builtin_amdgcn_s_setprio(1);
#pragma unroll
      for (int i = 0; i < 2; ++i) {
        oacc[i][0] = __builtin_amdgcn_mfma_f32_16x16x32_bf16(ap[i][ks], bv0, oacc[i][0], 0, 0, 0);
        oacc[i][1] = __builtin_amdgcn_mfma_f32_16x16x32_bf16(ap[i][ks], bv1, oacc[i][1], 0, 0, 0);
      }
      __builtin_amdgcn_s_setprio(0);
    }
  }
#undef ISSUE_KV

#pragma unroll
  for (int i = 0; i < 2; ++i) {
    tq[i] += __shfl_xor(tq[i], 16, 64);
    tq[i] += __shfl_xor(tq[i], 32, 64);
  }

  __syncthreads();
#pragma unroll
  for (int i = 0; i < 2; ++i) {
    float inv[4];
#pragma unroll
    for (int r = 0; r < 4; ++r)
      inv[r] = 1.0f / __shfl(tq[i], lg * 4 + r, 64);
#pragma unroll
    for (int jj = 0; jj < 2; ++jj)
#pragma unroll
      for (int r = 0; r < 4; ++r) {
        const int row = (w & 3) * 32 + i * 16 + lg * 4 + r;
        obuf[hw * 4224 + row * 33 + jj * 16 + lr] = oacc[i][jj][r] * inv[r];
      }
  }
  __syncthreads();

  {
    const int row = t >> 2;
    const int c8 = (t & 3) * 8;
    ushort8 vs, vd;
#pragma unroll
    for (int e = 0; e < 8; ++e) {
      const float o0 = obuf[0 * 4224 + row * 33 + c8 + e];
      const float o1 = obuf[1 * 4224 + row * 33 + c8 + e];
      vs[e] = f2b(o0 + o1);
      vd[e] = f2b(o0 - o1);
    }
    const size_t rowg = bbase + (size_t)(qb * 128 + row) * 1024;
    *(ushort8*)&Osd[rowg + hp * 32 + c8] = vs;
    *(ushort8*)&Osd[rowg + 512 + hp * 32 + c8] = vd;
  }
}

// ---------------------------------------------------------------------------
// Spectral output projection R14 (m97 cadence): 64m x 64sp, 256 thr (2M x 2half),
// K=512, BK=64 (8 K-tiles), single 32KB buffer:
//   Os[64][64]@0 | Od@4096 | Sp[64][64]@8192 | Dp@12288  (elems)
// Grid 512 = 2/CU uniform.
// ---------------------------------------------------------------------------
__global__ __launch_bounds__(256, 4) void gemm_out_sd(const ushort_t* __restrict__ Osd,
                                                      const ushort_t* __restrict__ Wsd,
                                                      float* __restrict__ out) {
  __shared__ ushort_t sh[16896];   // 32KB buffer; epi vd f32 [64][66] = 16896B fits

  const int t = threadIdx.x;
  const int w = t >> 6, lane = t & 63;
  const int wm = w >> 1, half = w & 1;
  const int lr = lane & 15, lg = lane >> 4;

  const int bid = blockIdx.x;                 // 512
  const int c = bid & 7, j = bid >> 3;
  const int mt = c * 8 + (j & 7);
  const int st = j >> 3;
  const int m0 = mt * 64, n0s = st * 64;

  f32x4 acc[2][4];
  const f32x4 fz = {0.f, 0.f, 0.f, 0.f};
#pragma unroll
  for (int mf = 0; mf < 2; ++mf)
#pragma unroll
    for (int nf = 0; nf < 4; ++nf) acc[mf][nf] = fz;

#define ISSUE_O(kt_)                                                                     \
  {                                                                                      \
    _Pragma("unroll") for (int rnd = 0; rnd < 2; ++rnd) {                                \
      const int ch = rnd * 256 + t;                                                      \
      const int row = ch >> 3, cs = ch & 7;                                              \
      const int gcol = (kt_) * 64 + ((cs ^ (row & 7)) << 3);                             \
      __builtin_amdgcn_global_load_lds(GPTR(Osd + (size_t)(m0 + row) * 1024 + gcol),     \
                                       LPTR(sh + (size_t)ch * 8), 16, 0, 0);             \
      __builtin_amdgcn_global_load_lds(GPTR(Osd + (size_t)(m0 + row) * 1024 + 512 + gcol),\
                                       LPTR(sh + 4096 + (size_t)ch * 8), 16, 0, 0);      \
      __builtin_amdgcn_global_load_lds(                                                  \
          GPTR(Wsd + (size_t)(3072 + n0s + row) * 512 + gcol),                           \
          LPTR(sh + 8192 + (size_t)ch * 8), 16, 0, 0);                                   \
      __builtin_amdgcn_global_load_lds(                                                  \
          GPTR(Wsd + (size_t)(3072 + 512 + n0s + row) * 512 + gcol),                     \
          LPTR(sh + 12288 + (size_t)ch * 8), 16, 0, 0);                                  \
    }                                                                                    \
  }

  const ushort_t* Asl = sh + half * 4096;           // Os or Od [64][64]
  const ushort_t* Bsl = sh + 8192 + half * 4096;    // Sp or Dp [64][64]

  for (int kt = 0; kt < 8; ++kt) {
    ISSUE_O(kt)
    asm volatile("s_waitcnt vmcnt(0)" ::: "memory");
    __builtin_amdgcn_sched_barrier(0);
    __builtin_amdgcn_s_barrier();
    asm volatile("" ::: "memory");

#pragma unroll
    for (int kk = 0; kk < 2; ++kk) {
      bf16x8 a[2], b[4];
#pragma unroll
      for (int mf = 0; mf < 2; ++mf) {
        const int row = wm * 32 + mf * 16 + lr;
        a[mf] = *(const bf16x8*)&Asl[row * 64 + (((kk * 4 + lg) ^ (row & 7)) << 3)];
      }
#pragma unroll
      for (int nf = 0; nf < 4; ++nf) {
        const int row = nf * 16 + lr;
        b[nf] = *(const bf16x8*)&Bsl[row * 64 + (((kk * 4 + lg) ^ (row & 7)) << 3)];
      }
      __builtin_amdgcn_s_setprio(1);
#pragma unroll
      for (int mf = 0; mf < 2; ++mf)
#pragma unroll
        for (int nf = 0; nf < 4; ++nf)
          acc[mf][nf] = __builtin_amdgcn_mfma_f32_16x16x32_bf16(a[mf], b[nf], acc[mf][nf], 0, 0, 0);
      __builtin_amdgcn_s_setprio(0);
    }
    asm volatile("s_waitcnt lgkmcnt(0)" ::: "memory");
    __builtin_amdgcn_sched_barrier(0);
    __builtin_amdgcn_s_barrier();
    asm volatile("" ::: "memory");
  }
#undef ISSUE_O

  // butterfly epilogue: vd waves -> LDS; us waves write y1/y2
  float* vdbuf = (float*)sh;    // [64][66]
  if (half == 1) {
#pragma unroll
    for (int mf = 0; mf < 2; ++mf)
#pragma unroll
      for (int nf = 0; nf < 4; ++nf)
#pragma unroll
        for (int rr = 0; rr < 4; ++rr) {
          const int row = wm * 32 + mf * 16 + lg * 4 + rr;
          const int col = nf * 16 + lr;
          vdbuf[row * 66 + col] = acc[mf][nf][rr];
        }
  }
  __syncthreads();
  if (half == 0) {
#pragma unroll
    for (int mf = 0; mf < 2; ++mf)
#pragma unroll
      for (int nf = 0; nf < 4; ++nf)
#pragma unroll
        for (int rr = 0; rr < 4; ++rr) {
          const int row = wm * 32 + mf * 16 + lg * 4 + rr;
          const int col = nf * 16 + lr;
          const float us = acc[mf][nf][rr];
          const float vd = vdbuf[row * 66 + col];
          out[(size_t)(m0 + row) * 1024 + n0s + col] = us + vd;
          out[(size_t)(m0 + row) * 1024 + 512 + n0s + col] = us - vd;
        }
  }
}

// ---------------------------------------------------------------------------
extern "C" void kernel_launch(void* const* d_in, const int* in_sizes, int n_in,
                              void* d_out, int out_size, void* d_ws, size_t ws_size,
                              hipStream_t stream) {
  const float* x   = (const float*)d_in[0];
  const float* wqA = (const float*)d_in[1];
  const float* wqB = (const float*)d_in[2];
  const float* wkA = (const float*)d_in[3];
  const float* wkB = (const float*)d_in[4];
  const float* wvA = (const float*)d_in[5];
  const float* wvB = (const float*)d_in[6];
  const float* wpA = (const float*)d_in[7];
  const float* wpB = (const float*)d_in[8];
  float* out = (float*)d_out;

  const size_t NE = (size_t)4096 * 1024;
  ushort_t* Qb   = (ushort_t*)d_ws;
  ushort_t* Kb   = Qb + NE;
  ushort_t* Vtb  = Kb + NE;
  ushort_t* xsd  = Vtb + NE;
  ushort_t* Wsd  = xsd + NE;                    // 4096x512 (Sq,Dq,Sk,Dk,Sv,Dv,Sp,Dp)
  ushort_t* Osd  = xsd;                         // alias: xsd dead after gemm_sd_qkv

  const float SCL = 0.17677669529663687f * 1.4426950408889634f;  // hd^-0.5 * log2e

  prep_k<<<2048, 256, 0, stream>>>(x, wqA, wqB, wkA, wkB, wvA, wvB, wpA, wpB,
                                   xsd, Wsd, SCL);
  gemm_sd_qkv<<<768, 256, 0, stream>>>(xsd, Wsd, Qb, Kb, Vtb);
  attn_k<<<512, 512, 0, stream>>>(Qb, Kb, Vtb, Osd);
  gemm_out_sd<<<512, 256, 0, stream>>>(Osd, Wsd, out);

  (void)in_sizes; (void)n_in; (void)out_size; (void)ws_size;
}

// Round 15
// 76.724 us; speedup vs baseline: 1.1044x; 1.0085x over previous
//
#include <hip/hip_runtime.h>

// EquAttentionPerChannel on MI355X (gfx950).
// R15: attn moved to paired-K-tile cadence (128 keys per sync window):
//      8 iterations x {barrier, stage next pair, vmcnt(4), barrier, compute
//      2 tiles} - barrier-pairs halved 16->8 (same mechanism as R14's BK=64
//      win). Everything else byte-identical to R14.

typedef unsigned short ushort_t;
typedef __attribute__((ext_vector_type(4))) unsigned short ushort4_t;
typedef __attribute__((ext_vector_type(8))) unsigned short ushort8;
typedef __attribute__((ext_vector_type(8))) __bf16 bf16x8;
typedef __attribute__((ext_vector_type(4))) float f32x4;
typedef __attribute__((ext_vector_type(4))) unsigned int uint4_t;

#define GPTR(p) ((const __attribute__((address_space(1))) void*)(p))
#define LPTR(p) ((__attribute__((address_space(3))) void*)(p))

static __device__ __forceinline__ unsigned short f2b(float f) {   // RNE
  unsigned int u = __builtin_bit_cast(unsigned int, f);
  unsigned int r = u + 0x7fffu + ((u >> 16) & 1u);
  return (unsigned short)(r >> 16);
}
static __device__ __forceinline__ float b2f(ushort_t h) {
  unsigned int u = ((unsigned int)h) << 16;
  return __builtin_bit_cast(float, u);
}
static __device__ __forceinline__ unsigned int pack2_rtna(float a, float b) {
  const unsigned int ra = __builtin_bit_cast(unsigned int, a) + 0x8000u;
  const unsigned int rb = __builtin_bit_cast(unsigned int, b) + 0x8000u;
  return __builtin_amdgcn_perm(rb, ra, 0x07060302u);  // [ra.b2,ra.b3,rb.b2,rb.b3]
}

// ---------------------------------------------------------------------------
// Prep (unchanged): xsd + Wsd = [Sq;Dq;Sk;Dk;Sv;Dv;Sp;Dp], Q pre-scaled.
// ---------------------------------------------------------------------------
__global__ __launch_bounds__(256) void prep_k(
    const float* __restrict__ x,
    const float* __restrict__ wqA, const float* __restrict__ wqB,
    const float* __restrict__ wkA, const float* __restrict__ wkB,
    const float* __restrict__ wvA, const float* __restrict__ wvB,
    const float* __restrict__ wpA, const float* __restrict__ wpB,
    ushort_t* __restrict__ xsd, ushort_t* __restrict__ Wsd, float sclq) {
  const int bid = blockIdx.x;
  if (bid < 1024) {
    const int u = bid * 256 + threadIdx.x;
    const int m = u >> 6;
    const int k8 = (u & 63) * 8;
    const float* p1 = x + (size_t)m * 1024 + k8;
    const float* p2 = p1 + 512;
    const f32x4 a0 = *(const f32x4*)p1,  a1 = *(const f32x4*)(p1 + 4);
    const f32x4 b0 = *(const f32x4*)p2,  b1 = *(const f32x4*)(p2 + 4);
    ushort8 vs, vd;
#pragma unroll
    for (int e = 0; e < 4; ++e) {
      vs[e] = f2b(a0[e] + b0[e]); vs[e + 4] = f2b(a1[e] + b1[e]);
      vd[e] = f2b(a0[e] - b0[e]); vd[e + 4] = f2b(a1[e] - b1[e]);
    }
    *(ushort8*)&xsd[(size_t)m * 1024 + k8] = vs;
    *(ushort8*)&xsd[(size_t)m * 1024 + 512 + k8] = vd;
  } else {
    const int u = (bid - 1024) * 256 + threadIdx.x;
    const int hm = u >> 15;
    const int rem = u & 32767;
    const int r = rem >> 6;
    const int c8 = (rem & 63) * 8;
    const int proj = hm >> 1, isD = hm & 1;
    const float* A; const float* B;
    if (proj == 0)      { A = wqA; B = wqB; }
    else if (proj == 1) { A = wkA; B = wkB; }
    else if (proj == 2) { A = wvA; B = wvB; }
    else                { A = wpA; B = wpB; }
    const float scl = 0.5f * (proj == 0 ? sclq : 1.0f);
    const f32x4 a0 = *(const f32x4*)(A + (size_t)r * 512 + c8);
    const f32x4 a1 = *(const f32x4*)(A + (size_t)r * 512 + c8 + 4);
    const f32x4 b0 = *(const f32x4*)(B + (size_t)r * 512 + c8);
    const f32x4 b1 = *(const f32x4*)(B + (size_t)r * 512 + c8 + 4);
    ushort8 v;
#pragma unroll
    for (int e = 0; e < 4; ++e) {
      v[e]     = f2b(isD ? (a0[e] - b0[e]) * scl : (a0[e] + b0[e]) * scl);
      v[e + 4] = f2b(isD ? (a1[e] - b1[e]) * scl : (a1[e] + b1[e]) * scl);
    }
    *(ushort8*)&Wsd[(size_t)(proj * 1024 + isD * 512 + r) * 512 + c8] = v;
  }
}

// ---------------------------------------------------------------------------
// Spectral QKV GEMM (unchanged from R14): 128m x 64sp, BK=64, m97 cadence,
// single 48KB buffer, grid 768 = 3 blocks/CU.
// ---------------------------------------------------------------------------
__global__ __launch_bounds__(256, 3) void gemm_sd_qkv(const ushort_t* __restrict__ xsd,
                                                      const ushort_t* __restrict__ Wsd,
                                                      ushort_t* __restrict__ Qb,
                                                      ushort_t* __restrict__ Kb,
                                                      ushort_t* __restrict__ Vtb) {
  __shared__ ushort_t sh[24576];

  const int t = threadIdx.x;
  const int wid = t >> 6, lane = t & 63;
  const int wm = wid >> 1, half = wid & 1;
  const int lr = lane & 15, lg = lane >> 4;

  const int bid = blockIdx.x;            // 768
  const int c = bid & 7, j = bid >> 3;
  const int mt = c * 4 + (j & 3);
  const int nzt = j >> 2;
  const int z = nzt >> 3;
  const int n0 = (nzt & 7) * 64;
  const int m0 = mt * 128;

  f32x4 acc[4][4];
  const f32x4 fz = {0.f, 0.f, 0.f, 0.f};
#pragma unroll
  for (int mf = 0; mf < 4; ++mf)
#pragma unroll
    for (int nf = 0; nf < 4; ++nf) acc[mf][nf] = fz;

#define ISSUE(kt_)                                                                       \
  {                                                                                      \
    _Pragma("unroll") for (int rnd = 0; rnd < 4; ++rnd) {                                \
      const int ch = rnd * 256 + t;                                                      \
      const int row = ch >> 3, cs = ch & 7;                                              \
      const int gcol = (kt_) * 64 + ((cs ^ (row & 7)) << 3);                             \
      __builtin_amdgcn_global_load_lds(GPTR(xsd + (size_t)(m0 + row) * 1024 + gcol),     \
                                       LPTR(sh + (size_t)ch * 8), 16, 0, 0);             \
      __builtin_amdgcn_global_load_lds(GPTR(xsd + (size_t)(m0 + row) * 1024 + 512 + gcol),\
                                       LPTR(sh + 8192 + (size_t)ch * 8), 16, 0, 0);      \
    }                                                                                    \
    _Pragma("unroll") for (int rnd = 0; rnd < 2; ++rnd) {                                \
      const int ch = rnd * 256 + t;                                                      \
      const int row = ch >> 3, cs = ch & 7;                                              \
      const int gcol = (kt_) * 64 + ((cs ^ (row & 7)) << 3);                             \
      __builtin_amdgcn_global_load_lds(                                                  \
          GPTR(Wsd + (size_t)(z * 1024 + n0 + row) * 512 + gcol),                        \
          LPTR(sh + 16384 + (size_t)ch * 8), 16, 0, 0);                                  \
      __builtin_amdgcn_global_load_lds(                                                  \
          GPTR(Wsd + (size_t)(z * 1024 + 512 + n0 + row) * 512 + gcol),                  \
          LPTR(sh + 20480 + (size_t)ch * 8), 16, 0, 0);                                  \
    }                                                                                    \
  }

  const ushort_t* Asl = sh + half * 8192;
  const ushort_t* Bsl = sh + 16384 + half * 4096;

  for (int kt = 0; kt < 8; ++kt) {
    ISSUE(kt)
    asm volatile("s_waitcnt vmcnt(0)" ::: "memory");
    __builtin_amdgcn_sched_barrier(0);
    __builtin_amdgcn_s_barrier();
    asm volatile("" ::: "memory");

#pragma unroll
    for (int kk = 0; kk < 2; ++kk) {
      bf16x8 a[4], b[4];
#pragma unroll
      for (int mf = 0; mf < 4; ++mf) {
        const int row = wm * 64 + mf * 16 + lr;
        a[mf] = *(const bf16x8*)&Asl[row * 64 + (((kk * 4 + lg) ^ (row & 7)) << 3)];
      }
#pragma unroll
      for (int nf = 0; nf < 4; ++nf) {
        const int row = nf * 16 + lr;
        b[nf] = *(const bf16x8*)&Bsl[row * 64 + (((kk * 4 + lg) ^ (row & 7)) << 3)];
      }
      __builtin_amdgcn_s_setprio(1);
#pragma unroll
      for (int mf = 0; mf < 4; ++mf)
#pragma unroll
        for (int nf = 0; nf < 4; ++nf)
          acc[mf][nf] = __builtin_amdgcn_mfma_f32_16x16x32_bf16(a[mf], b[nf], acc[mf][nf], 0, 0, 0);
      __builtin_amdgcn_s_setprio(0);
    }
    asm volatile("s_waitcnt lgkmcnt(0)" ::: "memory");
    __builtin_amdgcn_sched_barrier(0);
    __builtin_amdgcn_s_barrier();
    asm volatile("" ::: "memory");
  }
#undef ISSUE

  const int PAD = (z < 2) ? 72 : 73;
  ushort_t* tus = sh;
  ushort_t* tvd = sh + 128 * PAD;
  {
    ushort_t* dst = half ? tvd : tus;
#pragma unroll
    for (int mf = 0; mf < 4; ++mf)
#pragma unroll
      for (int nf = 0; nf < 4; ++nf)
#pragma unroll
        for (int rr = 0; rr < 4; ++rr) {
          const int row = wm * 64 + mf * 16 + lg * 4 + rr;
          const int col = nf * 16 + lr;
          dst[row * PAD + col] = f2b(acc[mf][nf][rr]);
        }
  }
  __syncthreads();

  if (z < 2) {
    ushort_t* C = (z == 0) ? Qb : Kb;
#pragma unroll
    for (int it = 0; it < 4; ++it) {
      const int idx = it * 256 + t;
      const int row = idx >> 3;
      const int c8 = (idx & 7) * 8;
      const ushort8 u8 = *(const ushort8*)&tus[row * 72 + c8];
      const ushort8 v8 = *(const ushort8*)&tvd[row * 72 + c8];
      ushort8 y1, y2;
#pragma unroll
      for (int e = 0; e < 8; ++e) {
        const float us = b2f(u8[e]), vd = b2f(v8[e]);
        y1[e] = f2b(us + vd);
        y2[e] = f2b(us - vd);
      }
      *(ushort8*)&C[(size_t)(m0 + row) * 1024 + n0 + c8] = y1;
      *(ushort8*)&C[(size_t)(m0 + row) * 1024 + 512 + n0 + c8] = y2;
    }
  } else {
    const int bidx = m0 >> 10, tok0 = m0 & 1023;
#pragma unroll
    for (int it = 0; it < 4; ++it) {
      const int idx = it * 256 + t;
      const int cr = idx >> 4;
      const int mc = (idx & 15) * 8;
      float y1v[8], y2v[8];
#pragma unroll
      for (int e = 0; e < 8; ++e) {
        const float us = b2f(tus[(mc + e) * 73 + cr]);
        const float vd = b2f(tvd[(mc + e) * 73 + cr]);
        y1v[e] = us + vd;
        y2v[e] = us - vd;
      }
      const int k6 = mc & 63;
      const int base = (k6 & 0x20) | ((k6 & 8) << 1) | ((k6 & 0x10) >> 2);
      const size_t rb1 = (size_t)bidx * 1024 * 1024 + (size_t)(n0 + cr) * 1024 +
                         tok0 + (mc & ~63) + base;
      const size_t rb2 = (size_t)bidx * 1024 * 1024 + (size_t)(512 + n0 + cr) * 1024 +
                         tok0 + (mc & ~63) + base;
      ushort4_t lo1, hi1, lo2, hi2;
#pragma unroll
      for (int e = 0; e < 4; ++e) {
        lo1[e] = f2b(y1v[e]); hi1[e] = f2b(y1v[e + 4]);
        lo2[e] = f2b(y2v[e]); hi2[e] = f2b(y2v[e + 4]);
      }
      *(ushort4_t*)&Vtb[rb1] = lo1;  *(ushort4_t*)&Vtb[rb1 + 8] = hi1;
      *(ushort4_t*)&Vtb[rb2] = lo2;  *(ushort4_t*)&Vtb[rb2 + 8] = hi2;
    }
  }
}

// ---------------------------------------------------------------------------
// Flash attention R15: paired-K-tile cadence (128 keys/sync window).
// Head-paired (hp, hp+16), 512 thr; per-tile body identical to R14.
// ---------------------------------------------------------------------------
__global__ __launch_bounds__(512, 4) void attn_k(const ushort_t* __restrict__ Q,
                                                 const ushort_t* __restrict__ K,
                                                 const ushort_t* __restrict__ Vt,
                                                 ushort_t* __restrict__ Osd) {
  __shared__ ushort_t shmem[32768];
  ushort_t* KsL = shmem;
  ushort_t* VsL = shmem + 16384;
  float* obuf = (float*)shmem;

  const int t = threadIdx.x;
  const int w = t >> 6, lane = t & 63;
  const int hw = w >> 2;
  const int lr = lane & 15, lg = lane >> 4, lk8 = lg * 8;
  const int rkey = (lr >> 1) & 3;
  const int pkey = lr & 7;

  const int nlin = blockIdx.x;          // 0..511
  const int c = nlin & 7, j = nlin >> 3;
  const int p = c * 8 + (j >> 3);
  const int qb = j & 7;
  const int hp = p & 15, b = p >> 4;

  const size_t bbase = (size_t)b * 1024 * 1024;
  const size_t headc = (size_t)hp * 32 + hw * 512;
  const int q0 = qb * 128 + (w & 3) * 32;
  const f32x4 fzero = {0.f, 0.f, 0.f, 0.f};

  bf16x8 bq[2];
#pragma unroll
  for (int i = 0; i < 2; ++i)
    bq[i] = *(const bf16x8*)&Q[bbase + (size_t)(q0 + i * 16 + lr) * 1024 + headc + lk8];

  f32x4 oacc[2][2];
  float tq[2] = {0.f, 0.f};
#pragma unroll
  for (int i = 0; i < 2; ++i)
#pragma unroll
    for (int jj = 0; jj < 2; ++jj) oacc[i][jj] = fzero;

#define ISSUE_KV(kt_, s_)                                                                \
  {                                                                                      \
    ushort_t* Kd_ = KsL + (s_) * 4096;                                                   \
    ushort_t* Vd_ = VsL + (s_) * 4096;                                                   \
    const int hl = t >> 8, rem = t & 255;                                                \
    const size_t hc_ = (size_t)hp * 32 + hl * 512;                                       \
    const int krow = rem >> 2, kc = rem & 3;                                             \
    __builtin_amdgcn_global_load_lds(                                                    \
        GPTR(K + bbase + (size_t)((kt_) * 64 + krow) * 1024 + hc_ +                      \
             ((kc ^ ((krow >> 1) & 3)) << 3)),                                           \
        LPTR(Kd_ + (size_t)t * 8), 16, 0, 0);                                            \
    const int vrow = rem >> 3, vc = rem & 7;                                             \
    __builtin_amdgcn_global_load_lds(                                                    \
        GPTR(Vt + bbase + (size_t)(hc_ + vrow) * 1024 + (kt_) * 64 +                     \
             ((vc ^ (vrow & 7)) << 3)),                                                  \
        LPTR(Vd_ + (size_t)t * 8), 16, 0, 0);                                            \
  }

// per-tile compute body (identical math/order to R14's loop body)
#define TILE_BODY(kt_)                                                                   \
  {                                                                                      \
    const int s_ = (kt_) & 3;                                                            \
    const ushort_t* Ksb = KsL + s_ * 4096 + hw * 2048;                                   \
    const ushort_t* Vsb = VsL + s_ * 4096 + hw * 2048;                                   \
    bf16x8 ak[4];                                                                        \
    _Pragma("unroll") for (int kf = 0; kf < 4; ++kf)                                     \
      ak[kf] = *(const bf16x8*)&Ksb[(kf * 16 + lr) * 32 + ((lg ^ rkey) << 3)];           \
    bf16x8 ap[2][2];                                                                     \
    _Pragma("unroll") for (int i = 0; i < 2; ++i) {                                      \
      f32x4 s4[4];                                                                       \
      __builtin_amdgcn_s_setprio(1);                                                     \
      _Pragma("unroll") for (int kf = 0; kf < 4; ++kf)                                   \
        s4[kf] = __builtin_amdgcn_mfma_f32_16x16x32_bf16(ak[kf], bq[i], fzero, 0, 0, 0); \
      __builtin_amdgcn_s_setprio(0);                                                     \
      _Pragma("unroll") for (int ks = 0; ks < 2; ++ks) {                                 \
        const float p0 = __builtin_amdgcn_exp2f(s4[2 * ks][0]);                          \
        const float p1 = __builtin_amdgcn_exp2f(s4[2 * ks][1]);                          \
        const float p2 = __builtin_amdgcn_exp2f(s4[2 * ks][2]);                          \
        const float p3 = __builtin_amdgcn_exp2f(s4[2 * ks][3]);                          \
        const float p4 = __builtin_amdgcn_exp2f(s4[2 * ks + 1][0]);                      \
        const float p5 = __builtin_amdgcn_exp2f(s4[2 * ks + 1][1]);                      \
        const float p6 = __builtin_amdgcn_exp2f(s4[2 * ks + 1][2]);                      \
        const float p7 = __builtin_amdgcn_exp2f(s4[2 * ks + 1][3]);                      \
        tq[i] += ((p0 + p1) + (p2 + p3)) + ((p4 + p5) + (p6 + p7));                      \
        uint4_t u;                                                                       \
        u[0] = pack2_rtna(p0, p1);                                                       \
        u[1] = pack2_rtna(p2, p3);                                                       \
        u[2] = pack2_rtna(p4, p5);                                                       \
        u[3] = pack2_rtna(p6, p7);                                                       \
        ap[i][ks] = __builtin_bit_cast(bf16x8, u);                                       \
      }                                                                                  \
    }                                                                                    \
    _Pragma("unroll") for (int ks = 0; ks < 2; ++ks) {                                   \
      bf16x8 bv0 = *(const bf16x8*)&Vsb[(0 * 16 + lr) * 64 +                             \
                                        ((ks * 32 + lk8) ^ (pkey << 3))];                \
      bf16x8 bv1 = *(const bf16x8*)&Vsb[(1 * 16 + lr) * 64 +                             \
                                        ((ks * 32 + lk8) ^ (pkey << 3))];                \
      __builtin_amdgcn_s_setprio(1);                                                     \
      _Pragma("unroll") for (int i = 0; i < 2; ++i) {                                    \
        oacc[i][0] = __builtin_amdgcn_mfma_f32_16x16x32_bf16(ap[i][ks], bv0,             \
                                                             oacc[i][0], 0, 0, 0);       \
        oacc[i][1] = __builtin_amdgcn_mfma_f32_16x16x32_bf16(ap[i][ks], bv1,             \
                                                             oacc[i][1], 0, 0, 0);       \
      }                                                                                  \
      __builtin_amdgcn_s_setprio(0);                                                     \
    }                                                                                    \
  }

  // prologue: tiles 0,1 staged (4 loads/thread in flight)
  ISSUE_KV(0, 0) ISSUE_KV(1, 1)
  for (int it = 0; it < 8; ++it) {
    const int k0t = it * 2;
    asm volatile("" ::: "memory");
    __builtin_amdgcn_s_barrier();       // all waves done reading slots being overwritten
    asm volatile("" ::: "memory");
    if (it < 7) {
      ISSUE_KV(k0t + 2, (k0t + 2) & 3)
      ISSUE_KV(k0t + 3, (k0t + 3) & 3)
      asm volatile("s_waitcnt vmcnt(4)" ::: "memory");   // tiles k0t,k0t+1 landed
    } else {
      asm volatile("s_waitcnt vmcnt(0)" ::: "memory");
    }
    __builtin_amdgcn_sched_barrier(0);
    __builtin_amdgcn_s_barrier();
    asm volatile("" ::: "memory");

    TILE_BODY(k0t)
    TILE_BODY(k0t + 1)
  }
#undef TILE_BODY
#undef ISSUE_KV

#pragma unroll
  for (int i = 0; i < 2; ++i) {
    tq[i] += __shfl_xor(tq[i], 16, 64);
    tq[i] += __shfl_xor(tq[i], 32, 64);
  }

  __syncthreads();
#pragma unroll
  for (int i = 0; i < 2; ++i) {
    float inv[4];
#pragma unroll
    for (int r = 0; r < 4; ++r)
      inv[r] = 1.0f / __shfl(tq[i], lg * 4 + r, 64);
#pragma unroll
    for (int jj = 0; jj < 2; ++jj)
#pragma unroll
      for (int r = 0; r < 4; ++r) {
        const int row = (w & 3) * 32 + i * 16 + lg * 4 + r;
        obuf[hw * 4224 + row * 33 + jj * 16 + lr] = oacc[i][jj][r] * inv[r];
      }
  }
  __syncthreads();

  {
    const int row = t >> 2;
    const int c8 = (t & 3) * 8;
    ushort8 vs, vd;
#pragma unroll
    for (int e = 0; e < 8; ++e) {
      const float o0 = obuf[0 * 4224 + row * 33 + c8 + e];
      const float o1 = obuf[1 * 4224 + row * 33 + c8 + e];
      vs[e] = f2b(o0 + o1);
      vd[e] = f2b(o0 - o1);
    }
    const size_t rowg = bbase + (size_t)(qb * 128 + row) * 1024;
    *(ushort8*)&Osd[rowg + hp * 32 + c8] = vs;
    *(ushort8*)&Osd[rowg + 512 + hp * 32 + c8] = vd;
  }
}

// ---------------------------------------------------------------------------
// Spectral output projection (unchanged from R14): 64m x 64sp, BK=64,
// m97 cadence, single 32KB buffer, grid 512 = 2/CU.
// ---------------------------------------------------------------------------
__global__ __launch_bounds__(256, 4) void gemm_out_sd(const ushort_t* __restrict__ Osd,
                                                      const ushort_t* __restrict__ Wsd,
                                                      float* __restrict__ out) {
  __shared__ ushort_t sh[16896];

  const int t = threadIdx.x;
  const int w = t >> 6, lane = t & 63;
  const int wm = w >> 1, half = w & 1;
  const int lr = lane & 15, lg = lane >> 4;

  const int bid = blockIdx.x;                 // 512
  const int c = bid & 7, j = bid >> 3;
  const int mt = c * 8 + (j & 7);
  const int st = j >> 3;
  const int m0 = mt * 64, n0s = st * 64;

  f32x4 acc[2][4];
  const f32x4 fz = {0.f, 0.f, 0.f, 0.f};
#pragma unroll
  for (int mf = 0; mf < 2; ++mf)
#pragma unroll
    for (int nf = 0; nf < 4; ++nf) acc[mf][nf] = fz;

#define ISSUE_O(kt_)                                                                     \
  {                                                                                      \
    _Pragma("unroll") for (int rnd = 0; rnd < 2; ++rnd) {                                \
      const int ch = rnd * 256 + t;                                                      \
      const int row = ch >> 3, cs = ch & 7;                                              \
      const int gcol = (kt_) * 64 + ((cs ^ (row & 7)) << 3);                             \
      __builtin_amdgcn_global_load_lds(GPTR(Osd + (size_t)(m0 + row) * 1024 + gcol),     \
                                       LPTR(sh + (size_t)ch * 8), 16, 0, 0);             \
      __builtin_amdgcn_global_load_lds(GPTR(Osd + (size_t)(m0 + row) * 1024 + 512 + gcol),\
                                       LPTR(sh + 4096 + (size_t)ch * 8), 16, 0, 0);      \
      __builtin_amdgcn_global_load_lds(                                                  \
          GPTR(Wsd + (size_t)(3072 + n0s + row) * 512 + gcol),                           \
          LPTR(sh + 8192 + (size_t)ch * 8), 16, 0, 0);                                   \
      __builtin_amdgcn_global_load_lds(                                                  \
          GPTR(Wsd + (size_t)(3072 + 512 + n0s + row) * 512 + gcol),                     \
          LPTR(sh + 12288 + (size_t)ch * 8), 16, 0, 0);                                  \
    }                                                                                    \
  }

  const ushort_t* Asl = sh + half * 4096;
  const ushort_t* Bsl = sh + 8192 + half * 4096;

  for (int kt = 0; kt < 8; ++kt) {
    ISSUE_O(kt)
    asm volatile("s_waitcnt vmcnt(0)" ::: "memory");
    __builtin_amdgcn_sched_barrier(0);
    __builtin_amdgcn_s_barrier();
    asm volatile("" ::: "memory");

#pragma unroll
    for (int kk = 0; kk < 2; ++kk) {
      bf16x8 a[2], b[4];
#pragma unroll
      for (int mf = 0; mf < 2; ++mf) {
        const int row = wm * 32 + mf * 16 + lr;
        a[mf] = *(const bf16x8*)&Asl[row * 64 + (((kk * 4 + lg) ^ (row & 7)) << 3)];
      }
#pragma unroll
      for (int nf = 0; nf < 4; ++nf) {
        const int row = nf * 16 + lr;
        b[nf] = *(const bf16x8*)&Bsl[row * 64 + (((kk * 4 + lg) ^ (row & 7)) << 3)];
      }
      __builtin_amdgcn_s_setprio(1);
#pragma unroll
      for (int mf = 0; mf < 2; ++mf)
#pragma unroll
        for (int nf = 0; nf < 4; ++nf)
          acc[mf][nf] = __builtin_amdgcn_mfma_f32_16x16x32_bf16(a[mf], b[nf], acc[mf][nf], 0, 0, 0);
      __builtin_amdgcn_s_setprio(0);
    }
    asm volatile("s_waitcnt lgkmcnt(0)" ::: "memory");
    __builtin_amdgcn_sched_barrier(0);
    __builtin_amdgcn_s_barrier();
    asm volatile("" ::: "memory");
  }
#undef ISSUE_O

  float* vdbuf = (float*)sh;
  if (half == 1) {
#pragma unroll
    for (int mf = 0; mf < 2; ++mf)
#pragma unroll
      for (int nf = 0; nf < 4; ++nf)
#pragma unroll
        for (int rr = 0; rr < 4; ++rr) {
          const int row = wm * 32 + mf * 16 + lg * 4 + rr;
          const int col = nf * 16 + lr;
          vdbuf[row * 66 + col] = acc[mf][nf][rr];
        }
  }
  __syncthreads();
  if (half == 0) {
#pragma unroll
    for (int mf = 0; mf < 2; ++mf)
#pragma unroll
      for (int nf = 0; nf < 4; ++nf)
#pragma unroll
        for (int rr = 0; rr < 4; ++rr) {
          const int row = wm * 32 + mf * 16 + lg * 4 + rr;
          const int col = nf * 16 + lr;
          const float us = acc[mf][nf][rr];
          const float vd = vdbuf[row * 66 + col];
          out[(size_t)(m0 + row) * 1024 + n0s + col] = us + vd;
          out[(size_t)(m0 + row) * 1024 + 512 + n0s + col] = us - vd;
        }
  }
}

// ---------------------------------------------------------------------------
extern "C" void kernel_launch(void* const* d_in, const int* in_sizes, int n_in,
                              void* d_out, int out_size, void* d_ws, size_t ws_size,
                              hipStream_t stream) {
  const float* x   = (const float*)d_in[0];
  const float* wqA = (const float*)d_in[1];
  const float* wqB = (const float*)d_in[2];
  const float* wkA = (const float*)d_in[3];
  const float* wkB = (const float*)d_in[4];
  const float* wvA = (const float*)d_in[5];
  const float* wvB = (const float*)d_in[6];
  const float* wpA = (const float*)d_in[7];
  const float* wpB = (const float*)d_in[8];
  float* out = (float*)d_out;

  const size_t NE = (size_t)4096 * 1024;
  ushort_t* Qb   = (ushort_t*)d_ws;
  ushort_t* Kb   = Qb + NE;
  ushort_t* Vtb  = Kb + NE;
  ushort_t* xsd  = Vtb + NE;
  ushort_t* Wsd  = xsd + NE;                    // 4096x512 (Sq,Dq,Sk,Dk,Sv,Dv,Sp,Dp)
  ushort_t* Osd  = xsd;                         // alias: xsd dead after gemm_sd_qkv

  const float SCL = 0.17677669529663687f * 1.4426950408889634f;  // hd^-0.5 * log2e

  prep_k<<<2048, 256, 0, stream>>>(x, wqA, wqB, wkA, wkB, wvA, wvB, wpA, wpB,
                                   xsd, Wsd, SCL);
  gemm_sd_qkv<<<768, 256, 0, stream>>>(xsd, Wsd, Qb, Kb, Vtb);
  attn_k<<<512, 512, 0, stream>>>(Qb, Kb, Vtb, Osd);
  gemm_out_sd<<<512, 256, 0, stream>>>(Osd, Wsd, out);

  (void)in_sizes; (void)n_in; (void)out_size; (void)ws_size;
}